// Round 1
// baseline (486.928 us; speedup 1.0000x reference)
//
#include <hip/hip_runtime.h>
#include <hip/hip_bf16.h>
#include <math.h>

#define NTOK 2048
#define CDIM 256
#define HHEADS 8
#define DHEAD 32
#define NEDGE 32768
#define ROWS 16
#define CT 128

// ---------------- LayerNorm: one block per row (256 threads, 1 elem/thread) ----
__global__ __launch_bounds__(256) void ln_kernel(const float* __restrict__ X,
    const float* __restrict__ g, const float* __restrict__ b, float* __restrict__ out)
{
    int row = blockIdx.x;
    int t = threadIdx.x;
    float x = X[(size_t)row * CDIM + t];

    __shared__ float red[4];
    __shared__ float stat[2];

    float s = x;
    #pragma unroll
    for (int off = 32; off > 0; off >>= 1) s += __shfl_down(s, off);
    if ((t & 63) == 0) red[t >> 6] = s;
    __syncthreads();
    if (t == 0) stat[0] = (red[0] + red[1] + red[2] + red[3]) * (1.0f / CDIM);
    __syncthreads();
    float mu = stat[0];
    float d = x - mu;
    float s2 = d * d;
    #pragma unroll
    for (int off = 32; off > 0; off >>= 1) s2 += __shfl_down(s2, off);
    if ((t & 63) == 0) red[t >> 6] = s2;
    __syncthreads();
    if (t == 0) stat[1] = rsqrtf((red[0] + red[1] + red[2] + red[3]) * (1.0f / CDIM) + 1e-5f);
    __syncthreads();
    out[(size_t)row * CDIM + t] = d * stat[1] * g[t] + b[t];
}

// ---------------- Generic fp32 tiled GEMM: C = act(A@B + bias) (+ resid) -------
// A[M,K] row-major, B[K,N] row-major. BM=BN=64, BK=16, 256 threads, 4x4/thread.
template<int ACT>
__global__ __launch_bounds__(256) void gemm_kernel(
    const float* __restrict__ A, const float* __restrict__ B,
    const float* __restrict__ bias, const float* __restrict__ resid,
    float* __restrict__ C, int M, int Nn, int K)
{
    const int BM = 64, BN = 64, BK = 16;
    __shared__ float As[BK][BM + 4];
    __shared__ float Bs[BK][BN + 4];

    int tid = threadIdx.x;
    int tx = tid & 15, ty = tid >> 4;
    int row0 = blockIdx.y * BM, col0 = blockIdx.x * BN;

    float acc[4][4] = {};

    for (int k0 = 0; k0 < K; k0 += BK) {
        // A tile: 64 rows x 16 k, float4/thread
        {
            int arow = tid >> 2, ak = (tid & 3) * 4;
            float4 a4 = *(const float4*)(A + (size_t)(row0 + arow) * K + k0 + ak);
            As[ak + 0][arow] = a4.x; As[ak + 1][arow] = a4.y;
            As[ak + 2][arow] = a4.z; As[ak + 3][arow] = a4.w;
            int brow = tid >> 4, bc = (tid & 15) * 4;
            float4 b4 = *(const float4*)(B + (size_t)(k0 + brow) * Nn + col0 + bc);
            *(float4*)&Bs[brow][bc] = b4;
        }
        __syncthreads();
        #pragma unroll
        for (int kk = 0; kk < BK; kk++) {
            float4 a4 = *(const float4*)&As[kk][ty * 4];
            float4 b4 = *(const float4*)&Bs[kk][tx * 4];
            float a[4] = {a4.x, a4.y, a4.z, a4.w};
            float b[4] = {b4.x, b4.y, b4.z, b4.w};
            #pragma unroll
            for (int i = 0; i < 4; i++)
                #pragma unroll
                for (int j = 0; j < 4; j++)
                    acc[i][j] += a[i] * b[j];
        }
        __syncthreads();
    }

    #pragma unroll
    for (int i = 0; i < 4; i++) {
        int rr = row0 + ty * 4 + i;
        #pragma unroll
        for (int j = 0; j < 4; j++) {
            int cc = col0 + tx * 4 + j;
            float v = acc[i][j] + bias[cc];
            if (ACT == 1) v = 0.5f * v * (1.0f + erff(v * 0.70710678118654752f));
            if (resid) v += resid[(size_t)rr * Nn + cc];
            C[(size_t)rr * Nn + cc] = v;
        }
    }
}

// ---------------- Edge CSR build -----------------------------------------------
__global__ void edge_hist_kernel(const int* __restrict__ src, int* __restrict__ cnt, int E)
{
    int e = blockIdx.x * blockDim.x + threadIdx.x;
    if (e < E) atomicAdd(&cnt[src[e]], 1);
}

__global__ __launch_bounds__(256) void edge_scan_kernel(const int* __restrict__ cnt,
    int* __restrict__ row_ptr, int* __restrict__ wcur)
{
    __shared__ int sums[256];
    int t = threadIdx.x;
    int base = t * 8;
    int local[8];
    int s = 0;
    #pragma unroll
    for (int i = 0; i < 8; i++) { local[i] = s; s += cnt[base + i]; }
    sums[t] = s;
    __syncthreads();
    for (int off = 1; off < 256; off <<= 1) {
        int v = (t >= off) ? sums[t - off] : 0;
        __syncthreads();
        sums[t] += v;
        __syncthreads();
    }
    int excl = (t == 0) ? 0 : sums[t - 1];
    #pragma unroll
    for (int i = 0; i < 8; i++) {
        int r = excl + local[i];
        row_ptr[base + i] = r;
        wcur[base + i] = r;
    }
    if (t == 255) row_ptr[NTOK] = sums[255];
}

__global__ void edge_scatter_kernel(const int* __restrict__ src, const int* __restrict__ dst,
    const int* __restrict__ rel, int* __restrict__ wcur, int2* __restrict__ pairs, int E)
{
    int e = blockIdx.x * blockDim.x + threadIdx.x;
    if (e < E) {
        int s = src[e];
        int pos = atomicAdd(&wcur[s], 1);
        pairs[pos] = make_int2(dst[e], rel[e]);
    }
}

// ---------------- Fused flash attention with structural biases ------------------
// grid: (NTOK/ROWS, HHEADS), 256 threads. thread t: row r=t>>4, lane c=t&15.
// thread owns cols {c + 16*i} of each 128-col tile, and output dims {2c, 2c+1}.
__global__ __launch_bounds__(256) void attn_kernel(
    const float* __restrict__ q, const float* __restrict__ k, const float* __restrict__ v,
    const int* __restrict__ token_type, const float* __restrict__ time_vec,
    const int* __restrict__ seed_ptr,
    const float* __restrict__ adj_rel_bias, const float* __restrict__ typepair_bias,
    const float* __restrict__ temp_bias,
    const int* __restrict__ row_ptr, const int2* __restrict__ pairs,
    float* __restrict__ o)
{
    __shared__ float Kt[CT][36];
    __shared__ float Vt[CT][36];
    __shared__ float P[ROWS][132];
    __shared__ int ttm[CT];
    __shared__ float tcol[CT];

    int h = blockIdx.y;
    int n0 = blockIdx.x * ROWS;
    int t = threadIdx.x;
    int r = t >> 4;
    int c = t & 15;
    int n = n0 + r;
    int seed = seed_ptr[0];

    float qreg[DHEAD];
    const float* qp = q + (size_t)n * CDIM + h * DHEAD;
    #pragma unroll
    for (int d = 0; d < DHEAD; d++) qreg[d] = qp[d];

    int ttn = token_type[n];
    float tn = time_vec[n];
    bool temporal = (n < seed);
    int e0 = row_ptr[n], e1 = row_ptr[n + 1];

    float m_run = -INFINITY, l_run = 0.0f;
    float oacc0 = 0.0f, oacc1 = 0.0f;

    for (int tile = 0; tile < NTOK / CT; ++tile) {
        int m0 = tile * CT;
        // stage K/V tiles (128 x 32 each), float4 per slot
        for (int idx = t; idx < CT * 8; idx += 256) {
            int mm = idx >> 3, d4 = (idx & 7) * 4;
            float4 k4 = *(const float4*)(k + (size_t)(m0 + mm) * CDIM + h * DHEAD + d4);
            Kt[mm][d4 + 0] = k4.x; Kt[mm][d4 + 1] = k4.y; Kt[mm][d4 + 2] = k4.z; Kt[mm][d4 + 3] = k4.w;
            float4 v4 = *(const float4*)(v + (size_t)(m0 + mm) * CDIM + h * DHEAD + d4);
            Vt[mm][d4 + 0] = v4.x; Vt[mm][d4 + 1] = v4.y; Vt[mm][d4 + 2] = v4.z; Vt[mm][d4 + 3] = v4.w;
        }
        for (int idx = t; idx < CT; idx += 256) {
            ttm[idx] = token_type[m0 + idx];
            tcol[idx] = time_vec[m0 + idx];
        }
        __syncthreads();

        float s[8];
        #pragma unroll
        for (int i = 0; i < 8; i++) {
            int j = c + i * 16;
            float acc = 0.0f;
            #pragma unroll
            for (int d = 0; d < DHEAD; d += 4) {
                float4 k4 = *(const float4*)&Kt[j][d];
                acc += qreg[d] * k4.x + qreg[d + 1] * k4.y + qreg[d + 2] * k4.z + qreg[d + 3] * k4.w;
            }
            float sc = acc * 0.17677669529663687f;
            int tm = ttm[j];
            sc += typepair_bias[((ttn * 8 + tm) << 3) + h];
            if (temporal) {
                float dt = tcol[j] - tn;
                float ab = fabsf(dt) + 1e-6f;
                float sg = (dt > 0.0f) ? 1.0f : ((dt < 0.0f) ? -1.0f : 0.0f);
                float sl = sg * log1pf(ab);
                sl = fminf(fmaxf(sl, -5.0f), 5.0f);
                float norm = (sl + 5.0f) * (1.0f / (10.0f + 1e-9f));
                int bidx = (int)floorf(norm * 20.0f);
                bidx = min(max(bidx, 0), 20);
                sc += temp_bias[bidx * 8 + h];
            }
            s[i] = sc;
        }
        // sparse edge bias for this row within the tile
        for (int e = e0; e < e1; ++e) {
            int2 pr = pairs[e];
            int dloc = pr.x - m0;
            if ((unsigned)dloc < (unsigned)CT && (dloc & 15) == c) {
                s[dloc >> 4] += adj_rel_bias[pr.y * 8 + h];
            }
        }
        // online softmax (reduce across 16 lanes of this row)
        float tmax = s[0];
        #pragma unroll
        for (int i = 1; i < 8; i++) tmax = fmaxf(tmax, s[i]);
        #pragma unroll
        for (int mk = 1; mk < 16; mk <<= 1) tmax = fmaxf(tmax, __shfl_xor(tmax, mk));
        float m_new = fmaxf(m_run, tmax);
        float p_sum = 0.0f;
        #pragma unroll
        for (int i = 0; i < 8; i++) { s[i] = __expf(s[i] - m_new); p_sum += s[i]; }
        #pragma unroll
        for (int mk = 1; mk < 16; mk <<= 1) p_sum += __shfl_xor(p_sum, mk);
        float scale = __expf(m_run - m_new);
        l_run = l_run * scale + p_sum;
        m_run = m_new;
        oacc0 *= scale; oacc1 *= scale;
        #pragma unroll
        for (int i = 0; i < 8; i++) P[r][c + i * 16] = s[i];
        __syncthreads();
        // PV: each thread accumulates dims 2c, 2c+1 over all 128 cols
        #pragma unroll 8
        for (int j = 0; j < CT; j++) {
            float p = P[r][j];
            float2 vv = *(const float2*)&Vt[j][2 * c];
            oacc0 += p * vv.x;
            oacc1 += p * vv.y;
        }
        __syncthreads();
    }
    float invl = 1.0f / l_run;
    float* op = o + (size_t)n * CDIM + h * DHEAD;
    op[2 * c] = oacc0 * invl;
    op[2 * c + 1] = oacc1 * invl;
}

// ---------------- launch --------------------------------------------------------
extern "C" void kernel_launch(void* const* d_in, const int* in_sizes, int n_in,
                              void* d_out, int out_size, void* d_ws, size_t ws_size,
                              hipStream_t stream)
{
    (void)in_sizes; (void)n_in; (void)out_size; (void)ws_size;
    const float* X        = (const float*)d_in[0];
    const int* token_type = (const int*)d_in[1];
    const int* edge_src   = (const int*)d_in[2];
    const int* edge_dst   = (const int*)d_in[3];
    const int* edge_rel   = (const int*)d_in[4];
    const float* time_vec = (const float*)d_in[5];
    const int* seed_ptr   = (const int*)d_in[6];
    const float* Wq = (const float*)d_in[7];  const float* bq = (const float*)d_in[8];
    const float* Wk = (const float*)d_in[9];  const float* bk = (const float*)d_in[10];
    const float* Wv = (const float*)d_in[11]; const float* bv = (const float*)d_in[12];
    const float* Wo = (const float*)d_in[13]; const float* bo = (const float*)d_in[14];
    const float* ln1_g = (const float*)d_in[15]; const float* ln1_b = (const float*)d_in[16];
    const float* ln2_g = (const float*)d_in[17]; const float* ln2_b = (const float*)d_in[18];
    const float* W1 = (const float*)d_in[19]; const float* b1 = (const float*)d_in[20];
    const float* W2 = (const float*)d_in[21]; const float* b2 = (const float*)d_in[22];
    const float* adj_rel_bias  = (const float*)d_in[23];
    const float* typepair_bias = (const float*)d_in[24];
    const float* temp_bias     = (const float*)d_in[25];
    float* out = (float*)d_out;

    const size_t NC = (size_t)NTOK * CDIM;
    float* ws  = (float*)d_ws;
    float* h1  = ws;
    float* qb  = ws + NC;
    float* kb  = ws + 2 * NC;
    float* vb  = ws + 3 * NC;
    float* ob  = ws + 4 * NC;
    float* xb  = ws + 5 * NC;
    float* h2  = ws + 6 * NC;
    float* mid = ws + 7 * NC;                       // NTOK * 1024
    char* ib = (char*)(mid + (size_t)NTOK * 1024);
    int2* pairs  = (int2*)ib;                        // NEDGE
    int* cnt     = (int*)(pairs + NEDGE);            // NTOK
    int* row_ptr = cnt + NTOK;                       // NTOK+1
    int* wcur    = row_ptr + NTOK + 1;               // NTOK

    // LN1
    ln_kernel<<<NTOK, 256, 0, stream>>>(X, ln1_g, ln1_b, h1);

    // QKV projections
    dim3 gC(CDIM / 64, NTOK / 64);
    gemm_kernel<0><<<gC, 256, 0, stream>>>(h1, Wq, bq, nullptr, qb, NTOK, CDIM, CDIM);
    gemm_kernel<0><<<gC, 256, 0, stream>>>(h1, Wk, bk, nullptr, kb, NTOK, CDIM, CDIM);
    gemm_kernel<0><<<gC, 256, 0, stream>>>(h1, Wv, bv, nullptr, vb, NTOK, CDIM, CDIM);

    // edge CSR
    hipMemsetAsync(cnt, 0, NTOK * sizeof(int), stream);
    edge_hist_kernel<<<NEDGE / 256, 256, 0, stream>>>(edge_src, cnt, NEDGE);
    edge_scan_kernel<<<1, 256, 0, stream>>>(cnt, row_ptr, wcur);
    edge_scatter_kernel<<<NEDGE / 256, 256, 0, stream>>>(edge_src, edge_dst, edge_rel, wcur, pairs, NEDGE);

    // fused attention
    attn_kernel<<<dim3(NTOK / ROWS, HHEADS), 256, 0, stream>>>(
        qb, kb, vb, token_type, time_vec, seed_ptr,
        adj_rel_bias, typepair_bias, temp_bias, row_ptr, pairs, ob);

    // x = X + o @ Wo + bo
    gemm_kernel<0><<<gC, 256, 0, stream>>>(ob, Wo, bo, X, xb, NTOK, CDIM, CDIM);

    // LN2
    ln_kernel<<<NTOK, 256, 0, stream>>>(xb, ln2_g, ln2_b, h2);

    // FFN
    gemm_kernel<1><<<dim3(1024 / 64, NTOK / 64), 256, 0, stream>>>(h2, W1, b1, nullptr, mid, NTOK, 1024, CDIM);
    gemm_kernel<0><<<gC, 256, 0, stream>>>(mid, W2, b2, xb, out, NTOK, CDIM, 1024);
}

// Round 2
// 377.735 us; speedup vs baseline: 1.2891x; 1.2891x over previous
//
#include <hip/hip_runtime.h>
#include <hip/hip_bf16.h>
#include <math.h>

#define NTOK 2048
#define CDIM 256
#define HHEADS 8
#define DHEAD 32
#define NEDGE 32768

typedef __attribute__((ext_vector_type(8))) short short8;
typedef __attribute__((ext_vector_type(4))) float f32x4;

static __device__ inline short f2bf(float f) {
    __hip_bfloat16 h = __float2bfloat16(f);
    return *reinterpret_cast<short*>(&h);
}

// ---------------- LayerNorm: one block per row (256 threads, 1 elem/thread) ----
__global__ __launch_bounds__(256) void ln_kernel(const float* __restrict__ X,
    const float* __restrict__ g, const float* __restrict__ b, float* __restrict__ out)
{
    int row = blockIdx.x;
    int t = threadIdx.x;
    float x = X[(size_t)row * CDIM + t];

    __shared__ float red[4];
    __shared__ float stat[2];

    float s = x;
    #pragma unroll
    for (int off = 32; off > 0; off >>= 1) s += __shfl_down(s, off);
    if ((t & 63) == 0) red[t >> 6] = s;
    __syncthreads();
    if (t == 0) stat[0] = (red[0] + red[1] + red[2] + red[3]) * (1.0f / CDIM);
    __syncthreads();
    float mu = stat[0];
    float d = x - mu;
    float s2 = d * d;
    #pragma unroll
    for (int off = 32; off > 0; off >>= 1) s2 += __shfl_down(s2, off);
    if ((t & 63) == 0) red[t >> 6] = s2;
    __syncthreads();
    if (t == 0) stat[1] = rsqrtf((red[0] + red[1] + red[2] + red[3]) * (1.0f / CDIM) + 1e-5f);
    __syncthreads();
    out[(size_t)row * CDIM + t] = d * stat[1] * g[t] + b[t];
}

// ---------------- Generic fp32 tiled GEMM: C = act(A@B + bias) (+ resid) -------
template<int ACT>
__global__ __launch_bounds__(256) void gemm_kernel(
    const float* __restrict__ A, const float* __restrict__ B,
    const float* __restrict__ bias, const float* __restrict__ resid,
    float* __restrict__ C, int M, int Nn, int K)
{
    const int BM = 64, BN = 64, BK = 16;
    __shared__ float As[BK][BM + 4];
    __shared__ float Bs[BK][BN + 4];

    int tid = threadIdx.x;
    int tx = tid & 15, ty = tid >> 4;
    int row0 = blockIdx.y * BM, col0 = blockIdx.x * BN;

    float acc[4][4] = {};

    for (int k0 = 0; k0 < K; k0 += BK) {
        {
            int arow = tid >> 2, ak = (tid & 3) * 4;
            float4 a4 = *(const float4*)(A + (size_t)(row0 + arow) * K + k0 + ak);
            As[ak + 0][arow] = a4.x; As[ak + 1][arow] = a4.y;
            As[ak + 2][arow] = a4.z; As[ak + 3][arow] = a4.w;
            int brow = tid >> 4, bc = (tid & 15) * 4;
            float4 b4 = *(const float4*)(B + (size_t)(k0 + brow) * Nn + col0 + bc);
            *(float4*)&Bs[brow][bc] = b4;
        }
        __syncthreads();
        #pragma unroll
        for (int kk = 0; kk < BK; kk++) {
            float4 a4 = *(const float4*)&As[kk][ty * 4];
            float4 b4 = *(const float4*)&Bs[kk][tx * 4];
            float a[4] = {a4.x, a4.y, a4.z, a4.w};
            float b[4] = {b4.x, b4.y, b4.z, b4.w};
            #pragma unroll
            for (int i = 0; i < 4; i++)
                #pragma unroll
                for (int j = 0; j < 4; j++)
                    acc[i][j] += a[i] * b[j];
        }
        __syncthreads();
    }

    #pragma unroll
    for (int i = 0; i < 4; i++) {
        int rr = row0 + ty * 4 + i;
        #pragma unroll
        for (int j = 0; j < 4; j++) {
            int cc = col0 + tx * 4 + j;
            float v = acc[i][j] + bias[cc];
            if (ACT == 1) v = 0.5f * v * (1.0f + erff(v * 0.70710678118654752f));
            if (resid) v += resid[(size_t)rr * Nn + cc];
            C[(size_t)rr * Nn + cc] = v;
        }
    }
}

// ---------------- Edge CSR build -----------------------------------------------
__global__ void edge_hist_kernel(const int* __restrict__ src, int* __restrict__ cnt, int E)
{
    int e = blockIdx.x * blockDim.x + threadIdx.x;
    if (e < E) atomicAdd(&cnt[src[e]], 1);
}

__global__ __launch_bounds__(256) void edge_scan_kernel(const int* __restrict__ cnt,
    int* __restrict__ row_ptr, int* __restrict__ wcur)
{
    __shared__ int sums[256];
    int t = threadIdx.x;
    int base = t * 8;
    int local[8];
    int s = 0;
    #pragma unroll
    for (int i = 0; i < 8; i++) { local[i] = s; s += cnt[base + i]; }
    sums[t] = s;
    __syncthreads();
    for (int off = 1; off < 256; off <<= 1) {
        int v = (t >= off) ? sums[t - off] : 0;
        __syncthreads();
        sums[t] += v;
        __syncthreads();
    }
    int excl = (t == 0) ? 0 : sums[t - 1];
    #pragma unroll
    for (int i = 0; i < 8; i++) {
        int r = excl + local[i];
        row_ptr[base + i] = r;
        wcur[base + i] = r;
    }
    if (t == 255) row_ptr[NTOK] = sums[255];
}

__global__ void edge_scatter_kernel(const int* __restrict__ src, const int* __restrict__ dst,
    const int* __restrict__ rel, int* __restrict__ wcur, int2* __restrict__ pairs, int E)
{
    int e = blockIdx.x * blockDim.x + threadIdx.x;
    if (e < E) {
        int s = src[e];
        int pos = atomicAdd(&wcur[s], 1);
        pairs[pos] = make_int2(dst[e], rel[e]);
    }
}

// ---------------- MFMA flash attention with structural biases -------------------
// Block: 1 head x 64 Q-rows, 512 threads (8 waves). Wave w: rows (w&3)*16,
// col-half (w>>2)*64 of each 128-col K-tile. S staged in LDS for bias adds +
// softmax; P repacked bf16 in LDS for the PV MFMA. O halves combined at end.
#define QBLK 64
#define KBLK 128
#define LQ 40      // Q/K LDS row stride (bf16 elems), 80B: 16B-aligned, bank-balanced
#define LP 136     // P / Vt LDS row stride (bf16 elems), 272B
#define LS 132     // S LDS row stride (f32)

__global__ __launch_bounds__(512) void attn_mfma_kernel(
    const float* __restrict__ q, const float* __restrict__ k, const float* __restrict__ v,
    const int* __restrict__ token_type, const float* __restrict__ time_vec,
    const int* __restrict__ seed_ptr,
    const float* __restrict__ adj_rel_bias, const float* __restrict__ typepair_bias,
    const float* __restrict__ temp_bias,
    const int* __restrict__ row_ptr, const int2* __restrict__ pairs,
    float* __restrict__ o)
{
    __shared__ __align__(16) short Q_lds[QBLK * LQ];
    __shared__ __align__(16) short K_lds[KBLK * LQ];
    __shared__ __align__(16) short Vt_lds[DHEAD * LP];
    __shared__ __align__(16) float S_lds[QBLK * LS];     // reused as Opart[2][64][36] at end
    __shared__ __align__(16) short P_lds[QBLK * LP];
    __shared__ int   ttm_s[KBLK];
    __shared__ float tcol_s[KBLK];
    __shared__ float tt_h[64];
    __shared__ float temp_h[21];
    __shared__ float adj_h[12];
    __shared__ int   ttn_l[QBLK];
    __shared__ float tn_l[QBLK];
    __shared__ float scale_l[QBLK];
    __shared__ float l_lds[QBLK];

    const int h  = blockIdx.y;
    const int n0 = blockIdx.x * QBLK;
    const int t  = threadIdx.x;
    const int wid  = t >> 6;
    const int lane = t & 63;
    const int rowblk  = (wid & 3) * 16;
    const int colhalf = (wid >> 2) * 64;
    const int seed = seed_ptr[0];

    // ---- one-time staging: Q (scaled, bf16), per-row meta, per-head tables ----
    {
        int row = t >> 3, d0 = (t & 7) * 4;
        float4 q4 = *(const float4*)(q + (size_t)(n0 + row) * CDIM + h * DHEAD + d0);
        const float sc = 0.17677669529663687f; // 1/sqrt(32)
        Q_lds[row * LQ + d0 + 0] = f2bf(q4.x * sc);
        Q_lds[row * LQ + d0 + 1] = f2bf(q4.y * sc);
        Q_lds[row * LQ + d0 + 2] = f2bf(q4.z * sc);
        Q_lds[row * LQ + d0 + 3] = f2bf(q4.w * sc);
    }
    if (t < 64)  tt_h[t] = typepair_bias[t * HHEADS + h];
    if (t < 21)  temp_h[t] = temp_bias[t * HHEADS + h];
    if (t < 12)  adj_h[t] = adj_rel_bias[t * HHEADS + h];
    if (t < QBLK) { ttn_l[t] = token_type[n0 + t]; tn_l[t] = time_vec[n0 + t]; }

    int e0 = 0, e1 = 0;
    if (t < QBLK) { e0 = row_ptr[n0 + t]; e1 = row_ptr[n0 + t + 1]; }

    // softmax row state (threads grouped 8-per-row; replicated in the 8 lanes)
    const int sr = t >> 3;           // softmax row 0..63
    const int scs = (t & 7) * 16;    // this thread's 16-col slice
    float m_run = -INFINITY, l_run = 0.0f;

    f32x4 oacc[2] = {{0,0,0,0},{0,0,0,0}};

    for (int tile = 0; tile < NTOK / KBLK; ++tile) {
        const int m0 = tile * KBLK;

        // ---- stage K (bf16) and V^T (bf16), plus per-col meta ----
        {
            int mm = t >> 2, d0 = (t & 3) * 8;
            const float* kp = k + (size_t)(m0 + mm) * CDIM + h * DHEAD + d0;
            float4 a = *(const float4*)kp;
            float4 b = *(const float4*)(kp + 4);
            short kk[8] = { f2bf(a.x), f2bf(a.y), f2bf(a.z), f2bf(a.w),
                            f2bf(b.x), f2bf(b.y), f2bf(b.z), f2bf(b.w) };
            *(short8*)&K_lds[mm * LQ + d0] = *(short8*)kk;
            const float* vp = v + (size_t)(m0 + mm) * CDIM + h * DHEAD + d0;
            float4 c = *(const float4*)vp;
            float4 d = *(const float4*)(vp + 4);
            short vv[8] = { f2bf(c.x), f2bf(c.y), f2bf(c.z), f2bf(c.w),
                            f2bf(d.x), f2bf(d.y), f2bf(d.z), f2bf(d.w) };
            #pragma unroll
            for (int j = 0; j < 8; j++) Vt_lds[(d0 + j) * LP + mm] = vv[j];
        }
        if (t < KBLK) { ttm_s[t] = token_type[m0 + t]; tcol_s[t] = time_vec[m0 + t]; }
        __syncthreads();

        // ---- QK^T (MFMA) -> S_lds ----
        {
            short8 afrag = *(const short8*)&Q_lds[(rowblk + (lane & 15)) * LQ + (lane >> 4) * 8];
            f32x4 z = {0.0f, 0.0f, 0.0f, 0.0f};
            f32x4 acc[4];
            #pragma unroll
            for (int nf = 0; nf < 4; nf++) {
                short8 bfrag = *(const short8*)&K_lds[(colhalf + nf * 16 + (lane & 15)) * LQ + (lane >> 4) * 8];
                acc[nf] = __builtin_amdgcn_mfma_f32_16x16x32_bf16(afrag, bfrag, z, 0, 0, 0);
            }
            #pragma unroll
            for (int nf = 0; nf < 4; nf++)
                #pragma unroll
                for (int reg = 0; reg < 4; reg++)
                    S_lds[(rowblk + (lane >> 4) * 4 + reg) * LS + colhalf + nf * 16 + (lane & 15)] = acc[nf][reg];
        }
        __syncthreads();

        // ---- sparse edge bias scatter (one thread per row) ----
        if (t < QBLK) {
            for (int e = e0; e < e1; ++e) {
                int2 pr = pairs[e];
                int dloc = pr.x - m0;
                if ((unsigned)dloc < (unsigned)KBLK)
                    S_lds[t * LS + dloc] += adj_h[pr.y];
            }
        }
        __syncthreads();

        // ---- biases + online softmax -> P_lds (bf16), scale_l ----
        {
            const int n = n0 + sr;
            const int ttn = ttn_l[sr];
            const float tn = tn_l[sr];
            const bool temporal = (n < seed);
            float vals[16];
            #pragma unroll
            for (int i = 0; i < 16; i++) {
                int col = scs + i;
                float sv = S_lds[sr * LS + col] + tt_h[ttn * 8 + ttm_s[col]];
                if (temporal) {
                    float dt = tcol_s[col] - tn;
                    float ab = fabsf(dt) + 1e-6f;
                    float sg = (dt > 0.0f) ? 1.0f : ((dt < 0.0f) ? -1.0f : 0.0f);
                    float sl = sg * log1pf(ab);
                    sl = fminf(fmaxf(sl, -5.0f), 5.0f);
                    float norm = (sl + 5.0f) * (1.0f / (10.0f + 1e-9f));
                    int bidx = (int)floorf(norm * 20.0f);
                    bidx = min(max(bidx, 0), 20);
                    sv += temp_h[bidx];
                }
                vals[i] = sv;
            }
            float tmax = vals[0];
            #pragma unroll
            for (int i = 1; i < 16; i++) tmax = fmaxf(tmax, vals[i]);
            tmax = fmaxf(tmax, __shfl_xor(tmax, 1));
            tmax = fmaxf(tmax, __shfl_xor(tmax, 2));
            tmax = fmaxf(tmax, __shfl_xor(tmax, 4));
            float m_new = fmaxf(m_run, tmax);
            float psum = 0.0f;
            short ps[16];
            #pragma unroll
            for (int i = 0; i < 16; i++) {
                float p = __expf(vals[i] - m_new);
                psum += p;
                ps[i] = f2bf(p);
            }
            psum += __shfl_xor(psum, 1);
            psum += __shfl_xor(psum, 2);
            psum += __shfl_xor(psum, 4);
            float scale = __expf(m_run - m_new);
            l_run = l_run * scale + psum;
            m_run = m_new;
            *(short8*)&P_lds[sr * LP + scs]     = *(short8*)&ps[0];
            *(short8*)&P_lds[sr * LP + scs + 8] = *(short8*)&ps[8];
            if ((t & 7) == 0) scale_l[sr] = scale;
        }
        __syncthreads();

        // ---- PV (MFMA): rescale O, accumulate P x V over this wave's col-half ----
        {
            float sc[4];
            #pragma unroll
            for (int reg = 0; reg < 4; reg++) sc[reg] = scale_l[rowblk + (lane >> 4) * 4 + reg];
            #pragma unroll
            for (int nf = 0; nf < 2; nf++)
                #pragma unroll
                for (int reg = 0; reg < 4; reg++) oacc[nf][reg] *= sc[reg];
            #pragma unroll
            for (int ks = 0; ks < 2; ks++) {
                short8 pa = *(const short8*)&P_lds[(rowblk + (lane & 15)) * LP + colhalf + ks * 32 + (lane >> 4) * 8];
                #pragma unroll
                for (int nf = 0; nf < 2; nf++) {
                    short8 vb = *(const short8*)&Vt_lds[(nf * 16 + (lane & 15)) * LP + colhalf + ks * 32 + (lane >> 4) * 8];
                    oacc[nf] = __builtin_amdgcn_mfma_f32_16x16x32_bf16(pa, vb, oacc[nf], 0, 0, 0);
                }
            }
        }
        __syncthreads();
    }

    // ---- finalize: store l, combine the two col-half partials, write O ----
    if ((t & 7) == 0) l_lds[sr] = l_run;
    __syncthreads();   // also guards S_lds reuse below

    {
        float* Op = S_lds;  // [2][64][36]
        int half = wid >> 2;
        #pragma unroll
        for (int nf = 0; nf < 2; nf++)
            #pragma unroll
            for (int reg = 0; reg < 4; reg++)
                Op[half * QBLK * 36 + (rowblk + (lane >> 4) * 4 + reg) * 36 + nf * 16 + (lane & 15)] = oacc[nf][reg];
    }
    __syncthreads();

    {
        float* Op = S_lds;
        int row = t >> 3, d0 = (t & 7) * 4;
        float inv = 1.0f / l_lds[row];
        float* op = o + (size_t)(n0 + row) * CDIM + h * DHEAD;
        #pragma unroll
        for (int j = 0; j < 4; j++) {
            int d = d0 + j;
            op[d] = (Op[row * 36 + d] + Op[QBLK * 36 + row * 36 + d]) * inv;
        }
    }
}

// ---------------- launch --------------------------------------------------------
extern "C" void kernel_launch(void* const* d_in, const int* in_sizes, int n_in,
                              void* d_out, int out_size, void* d_ws, size_t ws_size,
                              hipStream_t stream)
{
    (void)in_sizes; (void)n_in; (void)out_size; (void)ws_size;
    const float* X        = (const float*)d_in[0];
    const int* token_type = (const int*)d_in[1];
    const int* edge_src   = (const int*)d_in[2];
    const int* edge_dst   = (const int*)d_in[3];
    const int* edge_rel   = (const int*)d_in[4];
    const float* time_vec = (const float*)d_in[5];
    const int* seed_ptr   = (const int*)d_in[6];
    const float* Wq = (const float*)d_in[7];  const float* bq = (const float*)d_in[8];
    const float* Wk = (const float*)d_in[9];  const float* bk = (const float*)d_in[10];
    const float* Wv = (const float*)d_in[11]; const float* bv = (const float*)d_in[12];
    const float* Wo = (const float*)d_in[13]; const float* bo = (const float*)d_in[14];
    const float* ln1_g = (const float*)d_in[15]; const float* ln1_b = (const float*)d_in[16];
    const float* ln2_g = (const float*)d_in[17]; const float* ln2_b = (const float*)d_in[18];
    const float* W1 = (const float*)d_in[19]; const float* b1 = (const float*)d_in[20];
    const float* W2 = (const float*)d_in[21]; const float* b2 = (const float*)d_in[22];
    const float* adj_rel_bias  = (const float*)d_in[23];
    const float* typepair_bias = (const float*)d_in[24];
    const float* temp_bias     = (const float*)d_in[25];
    float* out = (float*)d_out;

    const size_t NC = (size_t)NTOK * CDIM;
    float* ws  = (float*)d_ws;
    float* h1  = ws;
    float* qb  = ws + NC;
    float* kb  = ws + 2 * NC;
    float* vb  = ws + 3 * NC;
    float* ob  = ws + 4 * NC;
    float* xb  = ws + 5 * NC;
    float* h2  = ws + 6 * NC;
    float* mid = ws + 7 * NC;                       // NTOK * 1024
    char* ib = (char*)(mid + (size_t)NTOK * 1024);
    int2* pairs  = (int2*)ib;                        // NEDGE
    int* cnt     = (int*)(pairs + NEDGE);            // NTOK
    int* row_ptr = cnt + NTOK;                       // NTOK+1
    int* wcur    = row_ptr + NTOK + 1;               // NTOK

    // LN1
    ln_kernel<<<NTOK, 256, 0, stream>>>(X, ln1_g, ln1_b, h1);

    // QKV projections
    dim3 gC(CDIM / 64, NTOK / 64);
    gemm_kernel<0><<<gC, 256, 0, stream>>>(h1, Wq, bq, nullptr, qb, NTOK, CDIM, CDIM);
    gemm_kernel<0><<<gC, 256, 0, stream>>>(h1, Wk, bk, nullptr, kb, NTOK, CDIM, CDIM);
    gemm_kernel<0><<<gC, 256, 0, stream>>>(h1, Wv, bv, nullptr, vb, NTOK, CDIM, CDIM);

    // edge CSR
    hipMemsetAsync(cnt, 0, NTOK * sizeof(int), stream);
    edge_hist_kernel<<<NEDGE / 256, 256, 0, stream>>>(edge_src, cnt, NEDGE);
    edge_scan_kernel<<<1, 256, 0, stream>>>(cnt, row_ptr, wcur);
    edge_scatter_kernel<<<NEDGE / 256, 256, 0, stream>>>(edge_src, edge_dst, edge_rel, wcur, pairs, NEDGE);

    // fused MFMA attention
    attn_mfma_kernel<<<dim3(NTOK / QBLK, HHEADS), 512, 0, stream>>>(
        qb, kb, vb, token_type, time_vec, seed_ptr,
        adj_rel_bias, typepair_bias, temp_bias, row_ptr, pairs, ob);

    // x = X + o @ Wo + bo
    gemm_kernel<0><<<gC, 256, 0, stream>>>(ob, Wo, bo, X, xb, NTOK, CDIM, CDIM);

    // LN2
    ln_kernel<<<NTOK, 256, 0, stream>>>(xb, ln2_g, ln2_b, h2);

    // FFN
    gemm_kernel<1><<<dim3(1024 / 64, NTOK / 64), 256, 0, stream>>>(h2, W1, b1, nullptr, mid, NTOK, 1024, CDIM);
    gemm_kernel<0><<<gC, 256, 0, stream>>>(mid, W2, b2, xb, out, NTOK, CDIM, 1024);
}

// Round 4
// 237.719 us; speedup vs baseline: 2.0483x; 1.5890x over previous
//
#include <hip/hip_runtime.h>
#include <hip/hip_bf16.h>
#include <math.h>

#define NTOK 2048
#define CDIM 256
#define HHEADS 8
#define DHEAD 32
#define NEDGE 32768
#define NTILE 16          // NTOK / KBLK

typedef __attribute__((ext_vector_type(8))) short short8;
typedef __attribute__((ext_vector_type(4))) short short4v;
typedef __attribute__((ext_vector_type(4))) float f32x4;

static __device__ inline short f2bf(float f) {
    __hip_bfloat16 h = __float2bfloat16(f);
    return *reinterpret_cast<short*>(&h);
}
static __device__ inline float bf2f(short s) {
    unsigned int u = ((unsigned int)(unsigned short)s) << 16;
    return *reinterpret_cast<float*>(&u);
}

// ---------------- LayerNorm: one block per row, bf16 output --------------------
__global__ __launch_bounds__(256) void ln_kernel(const float* __restrict__ X,
    const float* __restrict__ g, const float* __restrict__ b, short* __restrict__ out)
{
    int row = blockIdx.x;
    int t = threadIdx.x;
    float x = X[(size_t)row * CDIM + t];

    __shared__ float red[4];
    __shared__ float stat[2];

    float s = x;
    #pragma unroll
    for (int off = 32; off > 0; off >>= 1) s += __shfl_down(s, off);
    if ((t & 63) == 0) red[t >> 6] = s;
    __syncthreads();
    if (t == 0) stat[0] = (red[0] + red[1] + red[2] + red[3]) * (1.0f / CDIM);
    __syncthreads();
    float mu = stat[0];
    float d = x - mu;
    float s2 = d * d;
    #pragma unroll
    for (int off = 32; off > 0; off >>= 1) s2 += __shfl_down(s2, off);
    if ((t & 63) == 0) red[t >> 6] = s2;
    __syncthreads();
    if (t == 0) stat[1] = rsqrtf((red[0] + red[1] + red[2] + red[3]) * (1.0f / CDIM) + 1e-5f);
    __syncthreads();
    out[(size_t)row * CDIM + t] = f2bf(d * stat[1] * g[t] + b[t]);
}

// ---------------- Transpose + bf16 convert: in[K][N] -> out[N][K] --------------
// SRCF = 0: f32 input, 1: bf16 (short) input.
template<int SRCF>
__global__ __launch_bounds__(256) void transpose_kernel(const void* __restrict__ in_,
    short* __restrict__ out, int K, int N)
{
    __shared__ float tile[64][65];
    int k0 = blockIdx.y * 64, n0 = blockIdx.x * 64;
    int t = threadIdx.x;
    int r0 = t >> 4, c0 = (t & 15) * 4;
    #pragma unroll
    for (int i = 0; i < 4; i++) {
        int r = r0 + i * 16;
        if (SRCF == 0) {
            const float* in = (const float*)in_;
            float4 v = *(const float4*)(in + (size_t)(k0 + r) * N + n0 + c0);
            tile[r][c0 + 0] = v.x; tile[r][c0 + 1] = v.y;
            tile[r][c0 + 2] = v.z; tile[r][c0 + 3] = v.w;
        } else {
            const short* in = (const short*)in_;
            short4v v = *(const short4v*)(in + (size_t)(k0 + r) * N + n0 + c0);
            tile[r][c0 + 0] = bf2f(v.x); tile[r][c0 + 1] = bf2f(v.y);
            tile[r][c0 + 2] = bf2f(v.z); tile[r][c0 + 3] = bf2f(v.w);
        }
    }
    __syncthreads();
    #pragma unroll
    for (int i = 0; i < 4; i++) {
        int nr = r0 + i * 16;            // output row (= input col)
        short o4[4];
        #pragma unroll
        for (int j = 0; j < 4; j++) o4[j] = f2bf(tile[c0 + j][nr]);
        *(short4v*)(out + (size_t)(n0 + nr) * K + k0 + c0) = *(short4v*)o4;
    }
}

// ---------------- bf16 MFMA GEMM, 64x64 tile, BK=32, 256 thr -------------------
// A[M][K] bf16, Bt[N][K] bf16 (pre-transposed). EPI: 2 = f32 out + resid,
// 3 = GELU -> bf16 out.
template<int EPI>
__global__ __launch_bounds__(256) void gemm_bf16_kernel(
    const short* __restrict__ A, const short* __restrict__ Bt,
    const float* __restrict__ bias, const float* __restrict__ resid,
    void* __restrict__ out_, int M, int N, int K)
{
    __shared__ short A_lds[64 * 40];
    __shared__ short B_lds[64 * 40];

    const int t = threadIdx.x;
    const int w = t >> 6, lane = t & 63, c = lane & 15, g = lane >> 4;
    const int row0 = blockIdx.y * 64, col0 = blockIdx.x * 64;
    const int arow = t >> 2, ak = (t & 3) * 8;

    f32x4 acc[4] = {};

    for (int k0 = 0; k0 < K; k0 += 32) {
        *(short8*)&A_lds[arow * 40 + ak] = *(const short8*)&A[(size_t)(row0 + arow) * K + k0 + ak];
        *(short8*)&B_lds[arow * 40 + ak] = *(const short8*)&Bt[(size_t)(col0 + arow) * K + k0 + ak];
        __syncthreads();
        short8 af = *(const short8*)&A_lds[(w * 16 + c) * 40 + g * 8];
        #pragma unroll
        for (int nf = 0; nf < 4; nf++) {
            short8 bf = *(const short8*)&B_lds[(nf * 16 + c) * 40 + g * 8];
            acc[nf] = __builtin_amdgcn_mfma_f32_16x16x32_bf16(af, bf, acc[nf], 0, 0, 0);
        }
        __syncthreads();
    }

    #pragma unroll
    for (int nf = 0; nf < 4; nf++) {
        #pragma unroll
        for (int reg = 0; reg < 4; reg++) {
            int row = row0 + w * 16 + g * 4 + reg;
            int col = col0 + nf * 16 + c;
            float v = acc[nf][reg] + bias[col];
            if (EPI == 2) {
                ((float*)out_)[(size_t)row * N + col] = v + resid[(size_t)row * N + col];
            } else { // GELU -> bf16
                v = 0.5f * v * (1.0f + erff(v * 0.70710678118654752f));
                ((short*)out_)[(size_t)row * N + col] = f2bf(v);
            }
        }
    }
}

// Fused QKV GEMM: N = 768 (q|k|v). q,k -> qk_bf16[2048][512] (q scaled),
// v -> v_bf16[2048][256].
__global__ __launch_bounds__(256) void gemm_qkv_kernel(
    const short* __restrict__ A, const short* __restrict__ Bt,
    const float* __restrict__ bq, const float* __restrict__ bk, const float* __restrict__ bv,
    short* __restrict__ qk, short* __restrict__ vout)
{
    const int K = CDIM;
    __shared__ short A_lds[64 * 40];
    __shared__ short B_lds[64 * 40];

    const int t = threadIdx.x;
    const int w = t >> 6, lane = t & 63, c = lane & 15, g = lane >> 4;
    const int row0 = blockIdx.y * 64, col0 = blockIdx.x * 64;
    const int arow = t >> 2, ak = (t & 3) * 8;

    f32x4 acc[4] = {};

    for (int k0 = 0; k0 < K; k0 += 32) {
        *(short8*)&A_lds[arow * 40 + ak] = *(const short8*)&A[(size_t)(row0 + arow) * K + k0 + ak];
        *(short8*)&B_lds[arow * 40 + ak] = *(const short8*)&Bt[(size_t)(col0 + arow) * K + k0 + ak];
        __syncthreads();
        short8 af = *(const short8*)&A_lds[(w * 16 + c) * 40 + g * 8];
        #pragma unroll
        for (int nf = 0; nf < 4; nf++) {
            short8 bf = *(const short8*)&B_lds[(nf * 16 + c) * 40 + g * 8];
            acc[nf] = __builtin_amdgcn_mfma_f32_16x16x32_bf16(af, bf, acc[nf], 0, 0, 0);
        }
        __syncthreads();
    }

    const int region = col0 >> 8;           // 0=q, 1=k, 2=v
    const int colr0 = col0 & 255;
    const float* bias = (region == 0) ? bq : (region == 1) ? bk : bv;
    #pragma unroll
    for (int nf = 0; nf < 4; nf++) {
        #pragma unroll
        for (int reg = 0; reg < 4; reg++) {
            int row = row0 + w * 16 + g * 4 + reg;
            int col = colr0 + nf * 16 + c;
            float v = acc[nf][reg] + bias[col];
            if (region == 0) v *= 0.17677669529663687f;   // 1/sqrt(32)
            short b = f2bf(v);
            if (region < 2) qk[(size_t)row * 512 + region * 256 + col] = b;
            else            vout[(size_t)row * 256 + col] = b;
        }
    }
}

// ---------------- Edge CSR build, bucketed by (src, dst>>7) --------------------
__global__ void edge_hist2_kernel(const int* __restrict__ src, const int* __restrict__ dst,
    int* __restrict__ cnt, int E)
{
    int e = blockIdx.x * blockDim.x + threadIdx.x;
    if (e < E) atomicAdd(&cnt[src[e] * NTILE + (dst[e] >> 7)], 1);
}

__global__ __launch_bounds__(256) void edge_scan2_kernel(const int* __restrict__ cnt,
    int* __restrict__ row_ptr, int* __restrict__ wcur)
{
    __shared__ int sums[256];
    int t = threadIdx.x;
    int base = t * 128;
    int s = 0;
    for (int i = 0; i < 128; i++) s += cnt[base + i];
    sums[t] = s;
    __syncthreads();
    for (int off = 1; off < 256; off <<= 1) {
        int v = (t >= off) ? sums[t - off] : 0;
        __syncthreads();
        sums[t] += v;
        __syncthreads();
    }
    int run = (t == 0) ? 0 : sums[t - 1];
    for (int i = 0; i < 128; i++) {
        row_ptr[base + i] = run;
        wcur[base + i] = run;
        run += cnt[base + i];
    }
    if (t == 255) row_ptr[NTOK * NTILE] = run;
}

__global__ void edge_scatter2_kernel(const int* __restrict__ src, const int* __restrict__ dst,
    const int* __restrict__ rel, int* __restrict__ wcur, int2* __restrict__ pairs, int E)
{
    int e = blockIdx.x * blockDim.x + threadIdx.x;
    if (e < E) {
        int d = dst[e];
        int pos = atomicAdd(&wcur[src[e] * NTILE + (d >> 7)], 1);
        pairs[pos] = make_int2(d, rel[e]);
    }
}

// ---------------- MFMA flash attention ----------------------------------------
// Block: 1 head x 32 Q-rows, 256 thr (4 waves). Wave w: rows (w&1)*16,
// col-half (w>>1)*64 of each 128-col K-tile. All inputs pre-converted bf16:
// qk[2048][512] (q scaled | k), vt[256][2048] (V^T). 4 barriers/tile.
#define QBLK 32
#define KBLK 128
#define LQ 40      // Q/K LDS row stride (bf16)
#define LP 136     // P / Vt LDS row stride (bf16)
#define LS 132     // S LDS row stride (f32)

__global__ __launch_bounds__(256) void attn_mfma_kernel(
    const short* __restrict__ qk, const short* __restrict__ vt,
    const int* __restrict__ token_type, const float* __restrict__ time_vec,
    const int* __restrict__ seed_ptr,
    const float* __restrict__ adj_rel_bias, const float* __restrict__ typepair_bias,
    const float* __restrict__ temp_bias,
    const int* __restrict__ row_ptr2, const int2* __restrict__ pairs2,
    short* __restrict__ o)
{
    __shared__ __align__(16) short Q_lds[QBLK * LQ];
    __shared__ __align__(16) short K_lds[KBLK * LQ];
    __shared__ __align__(16) short Vt_lds[DHEAD * LP];
    __shared__ __align__(16) float S_lds[QBLK * LS];   // reused as Opart[2][32][36]
    __shared__ __align__(16) short P_lds[QBLK * LP];
    __shared__ int   ttm_s[KBLK];
    __shared__ float tcol_s[KBLK];
    __shared__ float tt_h[64];
    __shared__ float temp_h[21];
    __shared__ float adj_h[12];
    __shared__ int   ttn_l[QBLK];
    __shared__ float tn_l[QBLK];
    __shared__ float scale_l[QBLK];
    __shared__ float l_lds[QBLK];

    const int h  = blockIdx.y;
    const int n0 = blockIdx.x * QBLK;
    const int t  = threadIdx.x;
    const int w = t >> 6, lane = t & 63, c = lane & 15, g = lane >> 4;
    const int rowblk  = (w & 1) * 16;
    const int colhalf = (w >> 1) * 64;
    const int seed = seed_ptr[0];

    // one-time staging
    {
        int row = t >> 3, d0 = (t & 7) * 4;
        *(short4v*)&Q_lds[row * LQ + d0] =
            *(const short4v*)&qk[(size_t)(n0 + row) * 512 + h * 32 + d0];
    }
    if (t < 64)  tt_h[t] = typepair_bias[t * HHEADS + h];
    if (t < 21)  temp_h[t] = temp_bias[t * HHEADS + h];
    if (t < 12)  adj_h[t] = adj_rel_bias[t * HHEADS + h];
    if (t < QBLK) { ttn_l[t] = token_type[n0 + t]; tn_l[t] = time_vec[n0 + t]; }

    const int sr = t >> 3;           // softmax row 0..31 (8 thr/row)
    const int scs = (t & 7) * 16;    // 16-col slice
    const int n_sm = n0 + sr;
    float m_run = -INFINITY, l_run = 0.0f;

    f32x4 oacc[2] = {{0,0,0,0},{0,0,0,0}};

    for (int tile = 0; tile < NTILE; ++tile) {
        const int m0 = tile * KBLK;

        // stage K (128 rows x 32 bf16) and V^T (32 rows x 128 bf16):
        // 2 threads/row for K, each writes TWO short8 (8 elems each) -> full 32.
        // 8 threads/row for Vt, each writes TWO short8 -> full 128 cols.
        {
            int row = t >> 1, koff = (t & 1) * 16;
            const short* kp = &qk[(size_t)(m0 + row) * 512 + 256 + h * 32 + koff];
            *(short8*)&K_lds[row * LQ + koff]     = *(const short8*)kp;
            *(short8*)&K_lds[row * LQ + koff + 8] = *(const short8*)(kp + 8);
            int d = t >> 3, moff = (t & 7) * 16;
            const short* vp = &vt[(size_t)(h * 32 + d) * NTOK + m0 + moff];
            *(short8*)&Vt_lds[d * LP + moff]     = *(const short8*)vp;
            *(short8*)&Vt_lds[d * LP + moff + 8] = *(const short8*)(vp + 8);
        }
        if (t < KBLK) { ttm_s[t] = token_type[m0 + t]; tcol_s[t] = time_vec[m0 + t]; }
        __syncthreads();

        // QK^T (MFMA) -> S_lds
        {
            short8 afrag = *(const short8*)&Q_lds[(rowblk + c) * LQ + g * 8];
            f32x4 z = {0.0f, 0.0f, 0.0f, 0.0f};
            #pragma unroll
            for (int nf = 0; nf < 4; nf++) {
                short8 bfrag = *(const short8*)&K_lds[(colhalf + nf * 16 + c) * LQ + g * 8];
                f32x4 acc = __builtin_amdgcn_mfma_f32_16x16x32_bf16(afrag, bfrag, z, 0, 0, 0);
                #pragma unroll
                for (int reg = 0; reg < 4; reg++)
                    S_lds[(rowblk + g * 4 + reg) * LS + colhalf + nf * 16 + c] = acc[reg];
            }
        }
        __syncthreads();

        // biases (typepair + temporal + sparse edges) + online softmax -> P_lds
        {
            const int ttn = ttn_l[sr];
            const float tn = tn_l[sr];
            const bool temporal = (n_sm < seed);
            float vals[16];
            #pragma unroll
            for (int i = 0; i < 16; i++) {
                int col = scs + i;
                float sv = S_lds[sr * LS + col] + tt_h[ttn * 8 + ttm_s[col]];
                if (temporal) {
                    float dt = tcol_s[col] - tn;
                    float ab = fabsf(dt) + 1e-6f;
                    float sg = (dt > 0.0f) ? 1.0f : ((dt < 0.0f) ? -1.0f : 0.0f);
                    float sl = sg * log1pf(ab);
                    sl = fminf(fmaxf(sl, -5.0f), 5.0f);
                    float norm = (sl + 5.0f) * (1.0f / (10.0f + 1e-9f));
                    int bidx = (int)floorf(norm * 20.0f);
                    bidx = min(max(bidx, 0), 20);
                    sv += temp_h[bidx];
                }
                vals[i] = sv;
            }
            // sparse edge bias, per-(row,tile) CSR (~1 edge avg)
            int e0 = row_ptr2[n_sm * NTILE + tile];
            int e1 = row_ptr2[n_sm * NTILE + tile + 1];
            for (int e = e0; e < e1; ++e) {
                int2 pr = pairs2[e];
                int dloc = pr.x & 127;
                if ((dloc >> 4) == (t & 7)) {
                    float ab_ = adj_h[pr.y];
                    int li = dloc & 15;
                    #pragma unroll
                    for (int i = 0; i < 16; i++) vals[i] += (i == li) ? ab_ : 0.0f;
                }
            }
            float tmax = vals[0];
            #pragma unroll
            for (int i = 1; i < 16; i++) tmax = fmaxf(tmax, vals[i]);
            tmax = fmaxf(tmax, __shfl_xor(tmax, 1));
            tmax = fmaxf(tmax, __shfl_xor(tmax, 2));
            tmax = fmaxf(tmax, __shfl_xor(tmax, 4));
            float m_new = fmaxf(m_run, tmax);
            float psum = 0.0f;
            short ps[16];
            #pragma unroll
            for (int i = 0; i < 16; i++) {
                float p = __expf(vals[i] - m_new);
                psum += p;
                ps[i] = f2bf(p);
            }
            psum += __shfl_xor(psum, 1);
            psum += __shfl_xor(psum, 2);
            psum += __shfl_xor(psum, 4);
            float scale = __expf(m_run - m_new);
            l_run = l_run * scale + psum;
            m_run = m_new;
            *(short8*)&P_lds[sr * LP + scs]     = *(short8*)&ps[0];
            *(short8*)&P_lds[sr * LP + scs + 8] = *(short8*)&ps[8];
            if ((t & 7) == 0) { scale_l[sr] = scale; l_lds[sr] = l_run; }
        }
        __syncthreads();

        // PV (MFMA): rescale O, accumulate over this wave's col-half
        {
            float sc[4];
            #pragma unroll
            for (int reg = 0; reg < 4; reg++) sc[reg] = scale_l[rowblk + g * 4 + reg];
            #pragma unroll
            for (int nf = 0; nf < 2; nf++)
                #pragma unroll
                for (int reg = 0; reg < 4; reg++) oacc[nf][reg] *= sc[reg];
            #pragma unroll
            for (int ks = 0; ks < 2; ks++) {
                short8 pa = *(const short8*)&P_lds[(rowblk + c) * LP + colhalf + ks * 32 + g * 8];
                #pragma unroll
                for (int nf = 0; nf < 2; nf++) {
                    short8 vb = *(const short8*)&Vt_lds[(nf * 16 + c) * LP + colhalf + ks * 32 + g * 8];
                    oacc[nf] = __builtin_amdgcn_mfma_f32_16x16x32_bf16(pa, vb, oacc[nf], 0, 0, 0);
                }
            }
        }
        __syncthreads();
    }

    // combine the two col-half partials, write O (bf16)
    {
        float* Op = S_lds;  // [2][32][36]
        int half = w >> 1;
        #pragma unroll
        for (int nf = 0; nf < 2; nf++)
            #pragma unroll
            for (int reg = 0; reg < 4; reg++)
                Op[half * QBLK * 36 + (rowblk + g * 4 + reg) * 36 + nf * 16 + c] = oacc[nf][reg];
    }
    __syncthreads();
    {
        float* Op = S_lds;
        int row = t >> 3, d0 = (t & 7) * 4;
        float inv = 1.0f / l_lds[row];
        short o4[4];
        #pragma unroll
        for (int j = 0; j < 4; j++) {
            int d = d0 + j;
            o4[j] = f2bf((Op[row * 36 + d] + Op[QBLK * 36 + row * 36 + d]) * inv);
        }
        *(short4v*)&o[(size_t)(n0 + row) * CDIM + h * DHEAD + d0] = *(short4v*)o4;
    }
}

// ---------------- launch --------------------------------------------------------
extern "C" void kernel_launch(void* const* d_in, const int* in_sizes, int n_in,
                              void* d_out, int out_size, void* d_ws, size_t ws_size,
                              hipStream_t stream)
{
    (void)in_sizes; (void)n_in; (void)out_size; (void)ws_size;
    const float* X        = (const float*)d_in[0];
    const int* token_type = (const int*)d_in[1];
    const int* edge_src   = (const int*)d_in[2];
    const int* edge_dst   = (const int*)d_in[3];
    const int* edge_rel   = (const int*)d_in[4];
    const float* time_vec = (const float*)d_in[5];
    const int* seed_ptr   = (const int*)d_in[6];
    const float* Wq = (const float*)d_in[7];  const float* bq = (const float*)d_in[8];
    const float* Wk = (const float*)d_in[9];  const float* bk = (const float*)d_in[10];
    const float* Wv = (const float*)d_in[11]; const float* bv = (const float*)d_in[12];
    const float* Wo = (const float*)d_in[13]; const float* bo = (const float*)d_in[14];
    const float* ln1_g = (const float*)d_in[15]; const float* ln1_b = (const float*)d_in[16];
    const float* ln2_g = (const float*)d_in[17]; const float* ln2_b = (const float*)d_in[18];
    const float* W1 = (const float*)d_in[19]; const float* b1 = (const float*)d_in[20];
    const float* W2 = (const float*)d_in[21]; const float* b2 = (const float*)d_in[22];
    const float* adj_rel_bias  = (const float*)d_in[23];
    const float* typepair_bias = (const float*)d_in[24];
    const float* temp_bias     = (const float*)d_in[25];
    float* out = (float*)d_out;

    char* base = (char*)d_ws;
    size_t off = 0;
    auto alloc = [&](size_t bytes) { char* p = base + off; off += (bytes + 255) & ~(size_t)255; return p; };
    short* qk_bf   = (short*)alloc((size_t)NTOK * 512 * 2);
    short* v_bf    = (short*)alloc((size_t)NTOK * 256 * 2);
    short* vt_bf   = (short*)alloc((size_t)256 * NTOK * 2);
    short* h1_bf   = (short*)alloc((size_t)NTOK * 256 * 2);
    short* h2_bf   = (short*)alloc((size_t)NTOK * 256 * 2);
    short* o_bf    = (short*)alloc((size_t)NTOK * 256 * 2);
    short* mid_bf  = (short*)alloc((size_t)NTOK * 1024 * 2);
    float* xb      = (float*)alloc((size_t)NTOK * 256 * 4);
    short* wt_qkv  = (short*)alloc((size_t)768 * 256 * 2);
    short* wot     = (short*)alloc((size_t)256 * 256 * 2);
    short* w1t     = (short*)alloc((size_t)1024 * 256 * 2);
    short* w2t     = (short*)alloc((size_t)256 * 1024 * 2);
    int2*  pairs2  = (int2*)alloc((size_t)NEDGE * 8);
    int*   cnt2    = (int*)alloc((size_t)NTOK * NTILE * 4);
    int*   rowptr2 = (int*)alloc(((size_t)NTOK * NTILE + 1) * 4);
    int*   wcur2   = (int*)alloc((size_t)NTOK * NTILE * 4);

    // weight transposes (f32 -> bf16)
    transpose_kernel<0><<<dim3(4, 4),  256, 0, stream>>>(Wq, wt_qkv,            256, 256);
    transpose_kernel<0><<<dim3(4, 4),  256, 0, stream>>>(Wk, wt_qkv + 256*256,  256, 256);
    transpose_kernel<0><<<dim3(4, 4),  256, 0, stream>>>(Wv, wt_qkv + 512*256,  256, 256);
    transpose_kernel<0><<<dim3(4, 4),  256, 0, stream>>>(Wo, wot,               256, 256);
    transpose_kernel<0><<<dim3(16, 4), 256, 0, stream>>>(W1, w1t,               256, 1024);
    transpose_kernel<0><<<dim3(4, 16), 256, 0, stream>>>(W2, w2t,               1024, 256);

    // LN1 -> bf16
    ln_kernel<<<NTOK, 256, 0, stream>>>(X, ln1_g, ln1_b, h1_bf);

    // fused QKV projection (q pre-scaled)
    gemm_qkv_kernel<<<dim3(12, 32), 256, 0, stream>>>(h1_bf, wt_qkv, bq, bk, bv, qk_bf, v_bf);

    // V^T for attention
    transpose_kernel<1><<<dim3(4, 32), 256, 0, stream>>>(v_bf, vt_bf, NTOK, 256);

    // edge CSR bucketed by (src, dst-tile)
    hipMemsetAsync(cnt2, 0, NTOK * NTILE * sizeof(int), stream);
    edge_hist2_kernel<<<NEDGE / 256, 256, 0, stream>>>(edge_src, edge_dst, cnt2, NEDGE);
    edge_scan2_kernel<<<1, 256, 0, stream>>>(cnt2, rowptr2, wcur2);
    edge_scatter2_kernel<<<NEDGE / 256, 256, 0, stream>>>(edge_src, edge_dst, edge_rel, wcur2, pairs2, NEDGE);

    // fused MFMA attention -> o (bf16)
    attn_mfma_kernel<<<dim3(NTOK / QBLK, HHEADS), 256, 0, stream>>>(
        qk_bf, vt_bf, token_type, time_vec, seed_ptr,
        adj_rel_bias, typepair_bias, temp_bias, rowptr2, pairs2, o_bf);

    // x = X + o @ Wo + bo   (f32 out)
    gemm_bf16_kernel<2><<<dim3(4, 32), 256, 0, stream>>>(o_bf, wot, bo, X, xb, NTOK, 256, 256);

    // LN2 -> bf16
    ln_kernel<<<NTOK, 256, 0, stream>>>(xb, ln2_g, ln2_b, h2_bf);

    // FFN
    gemm_bf16_kernel<3><<<dim3(16, 32), 256, 0, stream>>>(h2_bf, w1t, b1, nullptr, mid_bf, NTOK, 1024, 256);
    gemm_bf16_kernel<2><<<dim3(4, 32), 256, 0, stream>>>(mid_bf, w2t, b2, xb, out, NTOK, 256, 1024);
}

// Round 5
// 213.086 us; speedup vs baseline: 2.2851x; 1.1156x over previous
//
#include <hip/hip_runtime.h>
#include <hip/hip_bf16.h>
#include <math.h>

#define NTOK 2048
#define CDIM 256
#define HHEADS 8
#define DHEAD 32
#define NEDGE 32768
#define NTILE 16          // edge-CSR buckets per row (dst >> 7)

typedef __attribute__((ext_vector_type(8))) short short8;
typedef __attribute__((ext_vector_type(4))) short short4v;
typedef __attribute__((ext_vector_type(4))) float f32x4;

static __device__ inline short f2bf(float f) {
    __hip_bfloat16 h = __float2bfloat16(f);
    return *reinterpret_cast<short*>(&h);
}
static __device__ inline float bf2f(short s) {
    unsigned int u = ((unsigned int)(unsigned short)s) << 16;
    return *reinterpret_cast<float*>(&u);
}

// ---------------- LayerNorm: one block per row, bf16 output --------------------
__global__ __launch_bounds__(256) void ln_kernel(const float* __restrict__ X,
    const float* __restrict__ g, const float* __restrict__ b, short* __restrict__ out)
{
    int row = blockIdx.x;
    int t = threadIdx.x;
    float x = X[(size_t)row * CDIM + t];

    __shared__ float red[4];
    __shared__ float stat[2];

    float s = x;
    #pragma unroll
    for (int off = 32; off > 0; off >>= 1) s += __shfl_down(s, off);
    if ((t & 63) == 0) red[t >> 6] = s;
    __syncthreads();
    if (t == 0) stat[0] = (red[0] + red[1] + red[2] + red[3]) * (1.0f / CDIM);
    __syncthreads();
    float mu = stat[0];
    float d = x - mu;
    float s2 = d * d;
    #pragma unroll
    for (int off = 32; off > 0; off >>= 1) s2 += __shfl_down(s2, off);
    if ((t & 63) == 0) red[t >> 6] = s2;
    __syncthreads();
    if (t == 0) stat[1] = rsqrtf((red[0] + red[1] + red[2] + red[3]) * (1.0f / CDIM) + 1e-5f);
    __syncthreads();
    out[(size_t)row * CDIM + t] = f2bf(d * stat[1] * g[t] + b[t]);
}

// ---------------- Transpose + bf16 convert: in[K][N] -> out[N][K] --------------
template<int SRCF>
static __device__ inline void transpose_tile(const void* __restrict__ in_,
    short* __restrict__ out, int K, int N, int k0, int n0, int t)
{
    __shared__ float tile[64][65];
    int r0 = t >> 4, c0 = (t & 15) * 4;
    #pragma unroll
    for (int i = 0; i < 4; i++) {
        int r = r0 + i * 16;
        if (SRCF == 0) {
            const float* in = (const float*)in_;
            float4 v = *(const float4*)(in + (size_t)(k0 + r) * N + n0 + c0);
            tile[r][c0 + 0] = v.x; tile[r][c0 + 1] = v.y;
            tile[r][c0 + 2] = v.z; tile[r][c0 + 3] = v.w;
        } else {
            const short* in = (const short*)in_;
            short4v v = *(const short4v*)(in + (size_t)(k0 + r) * N + n0 + c0);
            tile[r][c0 + 0] = bf2f(v.x); tile[r][c0 + 1] = bf2f(v.y);
            tile[r][c0 + 2] = bf2f(v.z); tile[r][c0 + 3] = bf2f(v.w);
        }
    }
    __syncthreads();
    #pragma unroll
    for (int i = 0; i < 4; i++) {
        int nr = r0 + i * 16;
        short o4[4];
        #pragma unroll
        for (int j = 0; j < 4; j++) o4[j] = f2bf(tile[c0 + j][nr]);
        *(short4v*)(out + (size_t)(n0 + nr) * K + k0 + c0) = *(short4v*)o4;
    }
}

__global__ __launch_bounds__(256) void transpose_kernel(const short* __restrict__ in,
    short* __restrict__ out, int K, int N)
{
    transpose_tile<1>(in, out, K, N, blockIdx.y * 64, blockIdx.x * 64, threadIdx.x);
}

// all 6 weight transposes in one launch (192 blocks)
__global__ __launch_bounds__(256) void transpose_all_kernel(
    const float* __restrict__ Wq, const float* __restrict__ Wk,
    const float* __restrict__ Wv, const float* __restrict__ Wo,
    const float* __restrict__ W1, const float* __restrict__ W2,
    short* __restrict__ wt_qkv, short* __restrict__ wot,
    short* __restrict__ w1t, short* __restrict__ w2t)
{
    int b = blockIdx.x;
    const float* src; short* dst; int K, N, bx, by;
    if (b < 64) {
        int m = b >> 4, r = b & 15;
        src = (m == 0) ? Wq : (m == 1) ? Wk : (m == 2) ? Wv : Wo;
        dst = (m == 0) ? wt_qkv : (m == 1) ? wt_qkv + 256 * 256
            : (m == 2) ? wt_qkv + 512 * 256 : wot;
        K = 256; N = 256; bx = r & 3; by = r >> 2;
    } else if (b < 128) {
        int r = b - 64; src = W1; dst = w1t; K = 256; N = 1024; bx = r & 15; by = r >> 4;
    } else {
        int r = b - 128; src = W2; dst = w2t; K = 1024; N = 256; bx = r & 3; by = r >> 2;
    }
    transpose_tile<0>(src, dst, K, N, by * 64, bx * 64, threadIdx.x);
}

// ---------------- bf16 MFMA GEMM, 64x64 tile, BK=32, 256 thr -------------------
template<int EPI>
__global__ __launch_bounds__(256) void gemm_bf16_kernel(
    const short* __restrict__ A, const short* __restrict__ Bt,
    const float* __restrict__ bias, const float* __restrict__ resid,
    void* __restrict__ out_, int M, int N, int K)
{
    __shared__ short A_lds[64 * 40];
    __shared__ short B_lds[64 * 40];

    const int t = threadIdx.x;
    const int w = t >> 6, lane = t & 63, c = lane & 15, g = lane >> 4;
    const int row0 = blockIdx.y * 64, col0 = blockIdx.x * 64;
    const int arow = t >> 2, ak = (t & 3) * 8;

    f32x4 acc[4] = {};

    for (int k0 = 0; k0 < K; k0 += 32) {
        *(short8*)&A_lds[arow * 40 + ak] = *(const short8*)&A[(size_t)(row0 + arow) * K + k0 + ak];
        *(short8*)&B_lds[arow * 40 + ak] = *(const short8*)&Bt[(size_t)(col0 + arow) * K + k0 + ak];
        __syncthreads();
        short8 af = *(const short8*)&A_lds[(w * 16 + c) * 40 + g * 8];
        #pragma unroll
        for (int nf = 0; nf < 4; nf++) {
            short8 bf = *(const short8*)&B_lds[(nf * 16 + c) * 40 + g * 8];
            acc[nf] = __builtin_amdgcn_mfma_f32_16x16x32_bf16(af, bf, acc[nf], 0, 0, 0);
        }
        __syncthreads();
    }

    #pragma unroll
    for (int nf = 0; nf < 4; nf++) {
        #pragma unroll
        for (int reg = 0; reg < 4; reg++) {
            int row = row0 + w * 16 + g * 4 + reg;
            int col = col0 + nf * 16 + c;
            float v = acc[nf][reg] + bias[col];
            if (EPI == 2) {
                ((float*)out_)[(size_t)row * N + col] = v + resid[(size_t)row * N + col];
            } else {
                v = 0.5f * v * (1.0f + erff(v * 0.70710678118654752f));
                ((short*)out_)[(size_t)row * N + col] = f2bf(v);
            }
        }
    }
}

// Fused QKV GEMM
__global__ __launch_bounds__(256) void gemm_qkv_kernel(
    const short* __restrict__ A, const short* __restrict__ Bt,
    const float* __restrict__ bq, const float* __restrict__ bk, const float* __restrict__ bv,
    short* __restrict__ qk, short* __restrict__ vout)
{
    const int K = CDIM;
    __shared__ short A_lds[64 * 40];
    __shared__ short B_lds[64 * 40];

    const int t = threadIdx.x;
    const int w = t >> 6, lane = t & 63, c = lane & 15, g = lane >> 4;
    const int row0 = blockIdx.y * 64, col0 = blockIdx.x * 64;
    const int arow = t >> 2, ak = (t & 3) * 8;

    f32x4 acc[4] = {};

    for (int k0 = 0; k0 < K; k0 += 32) {
        *(short8*)&A_lds[arow * 40 + ak] = *(const short8*)&A[(size_t)(row0 + arow) * K + k0 + ak];
        *(short8*)&B_lds[arow * 40 + ak] = *(const short8*)&Bt[(size_t)(col0 + arow) * K + k0 + ak];
        __syncthreads();
        short8 af = *(const short8*)&A_lds[(w * 16 + c) * 40 + g * 8];
        #pragma unroll
        for (int nf = 0; nf < 4; nf++) {
            short8 bf = *(const short8*)&B_lds[(nf * 16 + c) * 40 + g * 8];
            acc[nf] = __builtin_amdgcn_mfma_f32_16x16x32_bf16(af, bf, acc[nf], 0, 0, 0);
        }
        __syncthreads();
    }

    const int region = col0 >> 8;
    const int colr0 = col0 & 255;
    const float* bias = (region == 0) ? bq : (region == 1) ? bk : bv;
    #pragma unroll
    for (int nf = 0; nf < 4; nf++) {
        #pragma unroll
        for (int reg = 0; reg < 4; reg++) {
            int row = row0 + w * 16 + g * 4 + reg;
            int col = colr0 + nf * 16 + c;
            float v = acc[nf][reg] + bias[col];
            if (region == 0) v *= 0.17677669529663687f;
            short bb = f2bf(v);
            if (region < 2) qk[(size_t)row * 512 + region * 256 + col] = bb;
            else            vout[(size_t)row * 256 + col] = bb;
        }
    }
}

// ---------------- Edge CSR build, bucketed by (src, dst>>7) --------------------
__global__ void edge_hist2_kernel(const int* __restrict__ src, const int* __restrict__ dst,
    int* __restrict__ cnt, int E)
{
    int e = blockIdx.x * blockDim.x + threadIdx.x;
    if (e < E) atomicAdd(&cnt[src[e] * NTILE + (dst[e] >> 7)], 1);
}

__global__ __launch_bounds__(256) void edge_scan2_kernel(const int* __restrict__ cnt,
    int* __restrict__ row_ptr, int* __restrict__ wcur)
{
    __shared__ int sums[256];
    int t = threadIdx.x;
    int base = t * 128;
    int s = 0;
    for (int i = 0; i < 128; i++) s += cnt[base + i];
    sums[t] = s;
    __syncthreads();
    for (int off = 1; off < 256; off <<= 1) {
        int v = (t >= off) ? sums[t - off] : 0;
        __syncthreads();
        sums[t] += v;
        __syncthreads();
    }
    int run = (t == 0) ? 0 : sums[t - 1];
    for (int i = 0; i < 128; i++) {
        row_ptr[base + i] = run;
        wcur[base + i] = run;
        run += cnt[base + i];
    }
    if (t == 255) row_ptr[NTOK * NTILE] = run;
}

__global__ void edge_scatter2_kernel(const int* __restrict__ src, const int* __restrict__ dst,
    const int* __restrict__ rel, int* __restrict__ wcur, int2* __restrict__ pairs, int E)
{
    int e = blockIdx.x * blockDim.x + threadIdx.x;
    if (e < E) {
        int d = dst[e];
        int pos = atomicAdd(&wcur[src[e] * NTILE + (d >> 7)], 1);
        pairs[pos] = make_int2(d, rel[e]);
    }
}

// ---------------- MFMA flash attention, swapped-QK^T, in-register softmax ------
// Block: 1 head x 32 Q-rows, 256 thr (4 waves). Wave wv: q-rows (wv&1)*16 + c,
// col-half (wv>>1)*128 of each 256-col K-tile. Swapped QK^T: lane (c,g) holds
// S[q=rowblk+c][m=colhalf+16*blk+4*g+reg] for blk 0..7 -> softmax lane-local.
// The two col-half waves keep independent (m,l,O); merged once at the end.
// 2 barriers per tile.
#define QBLK 32
#define KBLK 256
#define NT2 (NTOK / KBLK)   // 8 tiles

__global__ __launch_bounds__(256) void attn_mfma2_kernel(
    const short* __restrict__ qk, const short* __restrict__ vt,
    const int* __restrict__ token_type, const float* __restrict__ time_vec,
    const int* __restrict__ seed_ptr,
    const float* __restrict__ adj_rel_bias, const float* __restrict__ typepair_bias,
    const float* __restrict__ temp_bias,
    const int* __restrict__ row_ptr2, const int2* __restrict__ pairs2,
    short* __restrict__ o)
{
    __shared__ __align__(16) short Q_lds[QBLK * 40];
    __shared__ __align__(16) short K_lds[KBLK * 40];        // reused as Opart[2][32][36] f32
    __shared__ __align__(16) short Vt_lds[DHEAD * 264];
    __shared__ __align__(16) unsigned int P32[QBLK * 132];  // packed bf16 pairs
    __shared__ unsigned int ttm8[KBLK / 4];
    __shared__ float tcol_s[KBLK];
    __shared__ float tt_h[64];
    __shared__ float temp_h[21];
    __shared__ float adj_h[12];
    __shared__ float2 ml[2][QBLK];

    const int h  = blockIdx.y;
    const int n0 = blockIdx.x * QBLK;
    const int t  = threadIdx.x;
    const int wv = t >> 6, lane = t & 63, c = lane & 15, g = lane >> 4;
    const int rowblk = (wv & 1) * 16;
    const int half   = wv >> 1;
    const int colhalf = half * 128;          // token offset within tile
    const int seed = seed_ptr[0];
    const bool blockTemporal = (n0 < seed);

    // ---- one-time staging: Q, tables ----
    if (t < 128) {
        int row = t >> 2, off = (t & 3) * 8;
        *(short8*)&Q_lds[row * 40 + off] =
            *(const short8*)&qk[(size_t)(n0 + row) * 512 + h * 32 + off];
    }
    if (t < 64)  tt_h[t] = typepair_bias[t * HHEADS + h];
    if (t < 21)  temp_h[t] = temp_bias[t * HHEADS + h];
    if (t < 12)  adj_h[t] = adj_rel_bias[t * HHEADS + h];

    // per-lane row meta (row = n0 + rowblk + c)
    const int nrow = n0 + rowblk + c;
    const int ttn = token_type[nrow];
    const bool rowTemporal = (nrow < seed);
    const float tn = time_vec[nrow];

    float m_run = -INFINITY, l_run = 0.0f;
    f32x4 oacc[2] = {{0,0,0,0},{0,0,0,0}};
    const f32x4 zf = {0.0f, 0.0f, 0.0f, 0.0f};

    for (int tile = 0; tile < NT2; ++tile) {
        const int m0 = tile * KBLK;
        __syncthreads();   // prev PV done (and Q/tables visible on iter 0)

        // ---- stage K [256][32], V^T [32][256], packed types, times ----
        #pragma unroll
        for (int i = 0; i < 4; i++) {
            int s = t + i * 256;
            int row = s >> 2, off = (s & 3) * 8;
            *(short8*)&K_lds[row * 40 + off] =
                *(const short8*)&qk[(size_t)(m0 + row) * 512 + 256 + h * 32 + off];
        }
        #pragma unroll
        for (int i = 0; i < 4; i++) {
            int s = t + i * 256;
            int row = s >> 5, off = (s & 31) * 8;
            *(short8*)&Vt_lds[row * 264 + off] =
                *(const short8*)&vt[(size_t)(h * 32 + row) * NTOK + m0 + off];
        }
        if (t < 64) {
            int4 tt4 = *(const int4*)&token_type[m0 + t * 4];
            ttm8[t] = (unsigned)(tt4.x | (tt4.y << 8) | (tt4.z << 16) | (tt4.w << 24));
        }
        if (blockTemporal) tcol_s[t] = time_vec[m0 + t];
        __syncthreads();

        // ---- swapped QK^T: vals[blk*4+reg] = S[q=rowblk+c][colhalf+16blk+4g+reg]
        short8 qfrag = *(const short8*)&Q_lds[(rowblk + c) * 40 + g * 8];
        float vals[32];
        #pragma unroll
        for (int blk = 0; blk < 8; blk++) {
            short8 kf = *(const short8*)&K_lds[(colhalf + blk * 16 + c) * 40 + g * 8];
            f32x4 acc = __builtin_amdgcn_mfma_f32_16x16x32_bf16(kf, qfrag, zf, 0, 0, 0);
            #pragma unroll
            for (int reg = 0; reg < 4; reg++) vals[blk * 4 + reg] = acc[reg];
        }

        // ---- typepair bias (packed type bytes, 1 b32 per blk) ----
        #pragma unroll
        for (int blk = 0; blk < 8; blk++) {
            unsigned w4 = ttm8[half * 32 + blk * 4 + g];
            #pragma unroll
            for (int reg = 0; reg < 4; reg++) {
                int ty = (w4 >> (8 * reg)) & 0xFF;
                vals[blk * 4 + reg] += tt_h[ttn * 8 + ty];
            }
        }
        // ---- temporal bias (rows < seed only) ----
        if (rowTemporal) {
            #pragma unroll
            for (int blk = 0; blk < 8; blk++) {
                #pragma unroll
                for (int reg = 0; reg < 4; reg++) {
                    float dt = tcol_s[colhalf + blk * 16 + g * 4 + reg] - tn;
                    float ab = fabsf(dt) + 1e-6f;
                    float sg = (dt > 0.0f) ? 1.0f : ((dt < 0.0f) ? -1.0f : 0.0f);
                    float sl = sg * log1pf(ab);
                    sl = fminf(fmaxf(sl, -5.0f), 5.0f);
                    float norm = (sl + 5.0f) * (1.0f / (10.0f + 1e-9f));
                    int bidx = (int)floorf(norm * 20.0f);
                    bidx = min(max(bidx, 0), 20);
                    vals[blk * 4 + reg] += temp_h[bidx];
                }
            }
        }
        // ---- sparse edge bias: bucket (row, 128-granular) = tile*2 + half ----
        {
            int nidx = nrow * NTILE + tile * 2 + half;
            int e0 = row_ptr2[nidx], e1 = row_ptr2[nidx + 1];
            for (int e = e0; e < e1; ++e) {
                int2 pr = pairs2[e];
                int dloc = pr.x & 127;
                if (((dloc >> 2) & 3) == g) {
                    float ab = adj_h[pr.y];
                    int li = (dloc >> 4) * 4 + (dloc & 3);
                    #pragma unroll
                    for (int i = 0; i < 32; i++) vals[i] += (i == li) ? ab : 0.0f;
                }
            }
        }

        // ---- online softmax, lane-local row; reduce over 4 g-lanes ----
        float tmax = vals[0];
        #pragma unroll
        for (int i = 1; i < 32; i++) tmax = fmaxf(tmax, vals[i]);
        tmax = fmaxf(tmax, __shfl_xor(tmax, 16));
        tmax = fmaxf(tmax, __shfl_xor(tmax, 32));
        float m_new = fmaxf(m_run, tmax);
        float psum = 0.0f;
        #pragma unroll
        for (int i = 0; i < 32; i++) { vals[i] = __expf(vals[i] - m_new); psum += vals[i]; }
        psum += __shfl_xor(psum, 16);
        psum += __shfl_xor(psum, 32);
        float scale = __expf(m_run - m_new);
        m_run = m_new;
        l_run = l_run * scale + psum;

        // ---- pack P (bf16 pairs) into P32; same-wave consume, no barrier ----
        #pragma unroll
        for (int blk = 0; blk < 8; blk++) {
            #pragma unroll
            for (int r = 0; r < 2; r++) {
                unsigned lo = (unsigned short)f2bf(vals[blk * 4 + 2 * r]);
                unsigned hi = (unsigned short)f2bf(vals[blk * 4 + 2 * r + 1]);
                P32[(rowblk + c) * 132 + half * 64 + blk * 8 + g * 2 + r] = lo | (hi << 16);
            }
        }

        // ---- PV: rescale O, accumulate over this wave's 128-col half ----
        float scr[4];
        #pragma unroll
        for (int reg = 0; reg < 4; reg++) scr[reg] = __shfl(scale, 4 * g + reg);
        #pragma unroll
        for (int dblk = 0; dblk < 2; dblk++)
            #pragma unroll
            for (int reg = 0; reg < 4; reg++) oacc[dblk][reg] *= scr[reg];
        #pragma unroll
        for (int kc = 0; kc < 4; kc++) {
            short8 pa = *(const short8*)&P32[(rowblk + c) * 132 + half * 64 + kc * 16 + g * 4];
            #pragma unroll
            for (int dblk = 0; dblk < 2; dblk++) {
                short8 vb = *(const short8*)&Vt_lds[(dblk * 16 + c) * 264 + colhalf + kc * 32 + g * 8];
                oacc[dblk] = __builtin_amdgcn_mfma_f32_16x16x32_bf16(pa, vb, oacc[dblk], 0, 0, 0);
            }
        }
    }

    // ---- endgame: merge the two col-half partials ----
    __syncthreads();
    if (lane < 16) ml[half][rowblk + lane] = make_float2(m_run, l_run);
    __syncthreads();

    float* Op = (float*)K_lds;   // [2][32][36]
    #pragma unroll
    for (int reg = 0; reg < 4; reg++) {
        int rw = rowblk + 4 * g + reg;
        float2 a0 = ml[0][rw], a1 = ml[1][rw];
        float mm = fmaxf(a0.x, a1.x);
        float wh = __expf((half == 0 ? a0.x : a1.x) - mm);
        Op[half * 32 * 36 + rw * 36 + c]      = oacc[0][reg] * wh;
        Op[half * 32 * 36 + rw * 36 + 16 + c] = oacc[1][reg] * wh;
    }
    __syncthreads();

    {
        int row = t >> 3, d0 = (t & 7) * 4;
        float2 a0 = ml[0][row], a1 = ml[1][row];
        float mm = fmaxf(a0.x, a1.x);
        float w0 = __expf(a0.x - mm), w1 = __expf(a1.x - mm);
        float linv = 1.0f / (a0.y * w0 + a1.y * w1);
        float4 pa = *(const float4*)&Op[row * 36 + d0];
        float4 pb = *(const float4*)&Op[(32 + row) * 36 + d0];
        short o4[4];
        o4[0] = f2bf((pa.x + pb.x) * linv);
        o4[1] = f2bf((pa.y + pb.y) * linv);
        o4[2] = f2bf((pa.z + pb.z) * linv);
        o4[3] = f2bf((pa.w + pb.w) * linv);
        *(short4v*)&o[(size_t)(n0 + row) * CDIM + h * DHEAD + d0] = *(short4v*)o4;
    }
}

// ---------------- launch --------------------------------------------------------
extern "C" void kernel_launch(void* const* d_in, const int* in_sizes, int n_in,
                              void* d_out, int out_size, void* d_ws, size_t ws_size,
                              hipStream_t stream)
{
    (void)in_sizes; (void)n_in; (void)out_size; (void)ws_size;
    const float* X        = (const float*)d_in[0];
    const int* token_type = (const int*)d_in[1];
    const int* edge_src   = (const int*)d_in[2];
    const int* edge_dst   = (const int*)d_in[3];
    const int* edge_rel   = (const int*)d_in[4];
    const float* time_vec = (const float*)d_in[5];
    const int* seed_ptr   = (const int*)d_in[6];
    const float* Wq = (const float*)d_in[7];  const float* bq = (const float*)d_in[8];
    const float* Wk = (const float*)d_in[9];  const float* bk = (const float*)d_in[10];
    const float* Wv = (const float*)d_in[11]; const float* bv = (const float*)d_in[12];
    const float* Wo = (const float*)d_in[13]; const float* bo = (const float*)d_in[14];
    const float* ln1_g = (const float*)d_in[15]; const float* ln1_b = (const float*)d_in[16];
    const float* ln2_g = (const float*)d_in[17]; const float* ln2_b = (const float*)d_in[18];
    const float* W1 = (const float*)d_in[19]; const float* b1 = (const float*)d_in[20];
    const float* W2 = (const float*)d_in[21]; const float* b2 = (const float*)d_in[22];
    const float* adj_rel_bias  = (const float*)d_in[23];
    const float* typepair_bias = (const float*)d_in[24];
    const float* temp_bias     = (const float*)d_in[25];
    float* out = (float*)d_out;

    char* base = (char*)d_ws;
    size_t off = 0;
    auto alloc = [&](size_t bytes) { char* p = base + off; off += (bytes + 255) & ~(size_t)255; return p; };
    short* qk_bf   = (short*)alloc((size_t)NTOK * 512 * 2);
    short* v_bf    = (short*)alloc((size_t)NTOK * 256 * 2);
    short* vt_bf   = (short*)alloc((size_t)256 * NTOK * 2);
    short* h1_bf   = (short*)alloc((size_t)NTOK * 256 * 2);
    short* h2_bf   = (short*)alloc((size_t)NTOK * 256 * 2);
    short* o_bf    = (short*)alloc((size_t)NTOK * 256 * 2);
    short* mid_bf  = (short*)alloc((size_t)NTOK * 1024 * 2);
    float* xb      = (float*)alloc((size_t)NTOK * 256 * 4);
    short* wt_qkv  = (short*)alloc((size_t)768 * 256 * 2);
    short* wot     = (short*)alloc((size_t)256 * 256 * 2);
    short* w1t     = (short*)alloc((size_t)1024 * 256 * 2);
    short* w2t     = (short*)alloc((size_t)256 * 1024 * 2);
    int2*  pairs2  = (int2*)alloc((size_t)NEDGE * 8);
    int*   cnt2    = (int*)alloc((size_t)NTOK * NTILE * 4);
    int*   rowptr2 = (int*)alloc(((size_t)NTOK * NTILE + 1) * 4);
    int*   wcur2   = (int*)alloc((size_t)NTOK * NTILE * 4);

    // all weight transposes in one launch
    transpose_all_kernel<<<192, 256, 0, stream>>>(Wq, Wk, Wv, Wo, W1, W2,
                                                  wt_qkv, wot, w1t, w2t);

    // LN1 -> bf16
    ln_kernel<<<NTOK, 256, 0, stream>>>(X, ln1_g, ln1_b, h1_bf);

    // fused QKV projection (q pre-scaled)
    gemm_qkv_kernel<<<dim3(12, 32), 256, 0, stream>>>(h1_bf, wt_qkv, bq, bk, bv, qk_bf, v_bf);

    // V^T for attention
    transpose_kernel<<<dim3(4, 32), 256, 0, stream>>>(v_bf, vt_bf, NTOK, 256);

    // edge CSR bucketed by (src, dst>>7)
    hipMemsetAsync(cnt2, 0, NTOK * NTILE * sizeof(int), stream);
    edge_hist2_kernel<<<NEDGE / 256, 256, 0, stream>>>(edge_src, edge_dst, cnt2, NEDGE);
    edge_scan2_kernel<<<1, 256, 0, stream>>>(cnt2, rowptr2, wcur2);
    edge_scatter2_kernel<<<NEDGE / 256, 256, 0, stream>>>(edge_src, edge_dst, edge_rel, wcur2, pairs2, NEDGE);

    // fused MFMA attention -> o (bf16)
    attn_mfma2_kernel<<<dim3(NTOK / QBLK, HHEADS), 256, 0, stream>>>(
        qk_bf, vt_bf, token_type, time_vec, seed_ptr,
        adj_rel_bias, typepair_bias, temp_bias, rowptr2, pairs2, o_bf);

    // x = X + o @ Wo + bo   (f32 out)
    gemm_bf16_kernel<2><<<dim3(4, 32), 256, 0, stream>>>(o_bf, wot, bo, X, xb, NTOK, 256, 256);

    // LN2 -> bf16
    ln_kernel<<<NTOK, 256, 0, stream>>>(xb, ln2_g, ln2_b, h2_bf);

    // FFN
    gemm_bf16_kernel<3><<<dim3(16, 32), 256, 0, stream>>>(h2_bf, w1t, b1, nullptr, mid_bf, NTOK, 1024, 256);
    gemm_bf16_kernel<2><<<dim3(4, 32), 256, 0, stream>>>(mid_bf, w2t, b2, xb, out, NTOK, 256, 1024);
}

// Round 6
// 179.913 us; speedup vs baseline: 2.7065x; 1.1844x over previous
//
#include <hip/hip_runtime.h>
#include <hip/hip_bf16.h>
#include <math.h>

#define NTOK 2048
#define CDIM 256
#define HHEADS 8
#define DHEAD 32
#define NEDGE 32768
#define NTILE 16          // edge-CSR buckets per row (dst >> 7), 128-wide

typedef __attribute__((ext_vector_type(8))) short short8;
typedef __attribute__((ext_vector_type(4))) short short4v;
typedef __attribute__((ext_vector_type(4))) float f32x4;

static __device__ inline short f2bf(float f) {
    __hip_bfloat16 h = __float2bfloat16(f);
    return *reinterpret_cast<short*>(&h);
}
static __device__ inline float bf2f(short s) {
    unsigned int u = ((unsigned int)(unsigned short)s) << 16;
    return *reinterpret_cast<float*>(&u);
}

// ---------------- LayerNorm: one block per row, bf16 output --------------------
__global__ __launch_bounds__(256) void ln_kernel(const float* __restrict__ X,
    const float* __restrict__ g, const float* __restrict__ b, short* __restrict__ out)
{
    int row = blockIdx.x;
    int t = threadIdx.x;
    float x = X[(size_t)row * CDIM + t];

    __shared__ float red[4];
    __shared__ float stat[2];

    float s = x;
    #pragma unroll
    for (int off = 32; off > 0; off >>= 1) s += __shfl_down(s, off);
    if ((t & 63) == 0) red[t >> 6] = s;
    __syncthreads();
    if (t == 0) stat[0] = (red[0] + red[1] + red[2] + red[3]) * (1.0f / CDIM);
    __syncthreads();
    float mu = stat[0];
    float d = x - mu;
    float s2 = d * d;
    #pragma unroll
    for (int off = 32; off > 0; off >>= 1) s2 += __shfl_down(s2, off);
    if ((t & 63) == 0) red[t >> 6] = s2;
    __syncthreads();
    if (t == 0) stat[1] = rsqrtf((red[0] + red[1] + red[2] + red[3]) * (1.0f / CDIM) + 1e-5f);
    __syncthreads();
    out[(size_t)row * CDIM + t] = f2bf(d * stat[1] * g[t] + b[t]);
}

// ---------------- Transpose + bf16 convert: in[K][N] -> out[N][K] --------------
template<int SRCF>
static __device__ inline void transpose_tile(const void* __restrict__ in_,
    short* __restrict__ out, int K, int N, int k0, int n0, int t)
{
    __shared__ float tile[64][65];
    int r0 = t >> 4, c0 = (t & 15) * 4;
    #pragma unroll
    for (int i = 0; i < 4; i++) {
        int r = r0 + i * 16;
        if (SRCF == 0) {
            const float* in = (const float*)in_;
            float4 v = *(const float4*)(in + (size_t)(k0 + r) * N + n0 + c0);
            tile[r][c0 + 0] = v.x; tile[r][c0 + 1] = v.y;
            tile[r][c0 + 2] = v.z; tile[r][c0 + 3] = v.w;
        } else {
            const short* in = (const short*)in_;
            short4v v = *(const short4v*)(in + (size_t)(k0 + r) * N + n0 + c0);
            tile[r][c0 + 0] = bf2f(v.x); tile[r][c0 + 1] = bf2f(v.y);
            tile[r][c0 + 2] = bf2f(v.z); tile[r][c0 + 3] = bf2f(v.w);
        }
    }
    __syncthreads();
    #pragma unroll
    for (int i = 0; i < 4; i++) {
        int nr = r0 + i * 16;
        short o4[4];
        #pragma unroll
        for (int j = 0; j < 4; j++) o4[j] = f2bf(tile[c0 + j][nr]);
        *(short4v*)(out + (size_t)(n0 + nr) * K + k0 + c0) = *(short4v*)o4;
    }
}

__global__ __launch_bounds__(256) void transpose_kernel(const short* __restrict__ in,
    short* __restrict__ out, int K, int N)
{
    transpose_tile<1>(in, out, K, N, blockIdx.y * 64, blockIdx.x * 64, threadIdx.x);
}

// all 6 weight transposes in one launch (192 blocks)
__global__ __launch_bounds__(256) void transpose_all_kernel(
    const float* __restrict__ Wq, const float* __restrict__ Wk,
    const float* __restrict__ Wv, const float* __restrict__ Wo,
    const float* __restrict__ W1, const float* __restrict__ W2,
    short* __restrict__ wt_qkv, short* __restrict__ wot,
    short* __restrict__ w1t, short* __restrict__ w2t)
{
    int b = blockIdx.x;
    const float* src; short* dst; int K, N, bx, by;
    if (b < 64) {
        int m = b >> 4, r = b & 15;
        src = (m == 0) ? Wq : (m == 1) ? Wk : (m == 2) ? Wv : Wo;
        dst = (m == 0) ? wt_qkv : (m == 1) ? wt_qkv + 256 * 256
            : (m == 2) ? wt_qkv + 512 * 256 : wot;
        K = 256; N = 256; bx = r & 3; by = r >> 2;
    } else if (b < 128) {
        int r = b - 64; src = W1; dst = w1t; K = 256; N = 1024; bx = r & 15; by = r >> 4;
    } else {
        int r = b - 128; src = W2; dst = w2t; K = 1024; N = 256; bx = r & 3; by = r >> 2;
    }
    transpose_tile<0>(src, dst, K, N, by * 64, bx * 64, threadIdx.x);
}

// ---------------- bf16 MFMA GEMM, 64x64 tile, BK=32, 256 thr -------------------
template<int EPI>
__global__ __launch_bounds__(256) void gemm_bf16_kernel(
    const short* __restrict__ A, const short* __restrict__ Bt,
    const float* __restrict__ bias, const float* __restrict__ resid,
    void* __restrict__ out_, int M, int N, int K)
{
    __shared__ short A_lds[64 * 40];
    __shared__ short B_lds[64 * 40];

    const int t = threadIdx.x;
    const int w = t >> 6, lane = t & 63, c = lane & 15, g = lane >> 4;
    const int row0 = blockIdx.y * 64, col0 = blockIdx.x * 64;
    const int arow = t >> 2, ak = (t & 3) * 8;

    f32x4 acc[4] = {};

    for (int k0 = 0; k0 < K; k0 += 32) {
        *(short8*)&A_lds[arow * 40 + ak] = *(const short8*)&A[(size_t)(row0 + arow) * K + k0 + ak];
        *(short8*)&B_lds[arow * 40 + ak] = *(const short8*)&Bt[(size_t)(col0 + arow) * K + k0 + ak];
        __syncthreads();
        short8 af = *(const short8*)&A_lds[(w * 16 + c) * 40 + g * 8];
        #pragma unroll
        for (int nf = 0; nf < 4; nf++) {
            short8 bf = *(const short8*)&B_lds[(nf * 16 + c) * 40 + g * 8];
            acc[nf] = __builtin_amdgcn_mfma_f32_16x16x32_bf16(af, bf, acc[nf], 0, 0, 0);
        }
        __syncthreads();
    }

    #pragma unroll
    for (int nf = 0; nf < 4; nf++) {
        #pragma unroll
        for (int reg = 0; reg < 4; reg++) {
            int row = row0 + w * 16 + g * 4 + reg;
            int col = col0 + nf * 16 + c;
            float v = acc[nf][reg] + bias[col];
            if (EPI == 2) {
                ((float*)out_)[(size_t)row * N + col] = v + resid[(size_t)row * N + col];
            } else {
                v = 0.5f * v * (1.0f + erff(v * 0.70710678118654752f));
                ((short*)out_)[(size_t)row * N + col] = f2bf(v);
            }
        }
    }
}

// Fused QKV GEMM
__global__ __launch_bounds__(256) void gemm_qkv_kernel(
    const short* __restrict__ A, const short* __restrict__ Bt,
    const float* __restrict__ bq, const float* __restrict__ bk, const float* __restrict__ bv,
    short* __restrict__ qk, short* __restrict__ vout)
{
    const int K = CDIM;
    __shared__ short A_lds[64 * 40];
    __shared__ short B_lds[64 * 40];

    const int t = threadIdx.x;
    const int w = t >> 6, lane = t & 63, c = lane & 15, g = lane >> 4;
    const int row0 = blockIdx.y * 64, col0 = blockIdx.x * 64;
    const int arow = t >> 2, ak = (t & 3) * 8;

    f32x4 acc[4] = {};

    for (int k0 = 0; k0 < K; k0 += 32) {
        *(short8*)&A_lds[arow * 40 + ak] = *(const short8*)&A[(size_t)(row0 + arow) * K + k0 + ak];
        *(short8*)&B_lds[arow * 40 + ak] = *(const short8*)&Bt[(size_t)(col0 + arow) * K + k0 + ak];
        __syncthreads();
        short8 af = *(const short8*)&A_lds[(w * 16 + c) * 40 + g * 8];
        #pragma unroll
        for (int nf = 0; nf < 4; nf++) {
            short8 bf = *(const short8*)&B_lds[(nf * 16 + c) * 40 + g * 8];
            acc[nf] = __builtin_amdgcn_mfma_f32_16x16x32_bf16(af, bf, acc[nf], 0, 0, 0);
        }
        __syncthreads();
    }

    const int region = col0 >> 8;
    const int colr0 = col0 & 255;
    const float* bias = (region == 0) ? bq : (region == 1) ? bk : bv;
    #pragma unroll
    for (int nf = 0; nf < 4; nf++) {
        #pragma unroll
        for (int reg = 0; reg < 4; reg++) {
            int row = row0 + w * 16 + g * 4 + reg;
            int col = colr0 + nf * 16 + c;
            float v = acc[nf][reg] + bias[col];
            if (region == 0) v *= 0.17677669529663687f;
            short bb = f2bf(v);
            if (region < 2) qk[(size_t)row * 512 + region * 256 + col] = bb;
            else            vout[(size_t)row * 256 + col] = bb;
        }
    }
}

// ---------------- Edge CSR build, bucketed by (src, dst>>7) --------------------
__global__ void edge_hist2_kernel(const int* __restrict__ src, const int* __restrict__ dst,
    int* __restrict__ cnt, int E)
{
    int e = blockIdx.x * blockDim.x + threadIdx.x;
    if (e < E) atomicAdd(&cnt[src[e] * NTILE + (dst[e] >> 7)], 1);
}

__global__ __launch_bounds__(256) void edge_scan2_kernel(const int* __restrict__ cnt,
    int* __restrict__ row_ptr, int* __restrict__ wcur)
{
    __shared__ int sums[256];
    int t = threadIdx.x;
    int base = t * 128;
    int s = 0;
    for (int i = 0; i < 128; i++) s += cnt[base + i];
    sums[t] = s;
    __syncthreads();
    for (int off = 1; off < 256; off <<= 1) {
        int v = (t >= off) ? sums[t - off] : 0;
        __syncthreads();
        sums[t] += v;
        __syncthreads();
    }
    int run = (t == 0) ? 0 : sums[t - 1];
    for (int i = 0; i < 128; i++) {
        row_ptr[base + i] = run;
        wcur[base + i] = run;
        run += cnt[base + i];
    }
    if (t == 255) row_ptr[NTOK * NTILE] = run;
}

__global__ void edge_scatter2_kernel(const int* __restrict__ src, const int* __restrict__ dst,
    const int* __restrict__ rel, int* __restrict__ wcur, int2* __restrict__ pairs, int E)
{
    int e = blockIdx.x * blockDim.x + threadIdx.x;
    if (e < E) {
        int d = dst[e];
        int pos = atomicAdd(&wcur[src[e] * NTILE + (d >> 7)], 1);
        pairs[pos] = make_int2(d, rel[e]);
    }
}

// ---------------- MFMA flash attention: split-K + register prefetch ------------
// Grid (64, 8, SPLITS). Block: 1 head x 32 Q-rows x 512 tokens (4 tiles of 128),
// 256 thr (4 waves). Wave wv: q-rows (wv&1)*16 + c, col-half (wv>>1)*64.
// Swapped QK^T keeps softmax lane-local. Per-block partial (m, l, O-unnorm)
// written to ws; attn_reduce merges the SPLITS partials.
#define QBLK 32
#define KBLK 128
#define SPLITS 4
#define TPS 4              // tiles per split

__global__ __launch_bounds__(256) void attn_mfma3_kernel(
    const short* __restrict__ qk, const short* __restrict__ vt,
    const int* __restrict__ token_type, const float* __restrict__ time_vec,
    const int* __restrict__ seed_ptr,
    const float* __restrict__ adj_rel_bias, const float* __restrict__ typepair_bias,
    const float* __restrict__ temp_bias,
    const int* __restrict__ row_ptr2, const int2* __restrict__ pairs2,
    float* __restrict__ Op_part, float2* __restrict__ ml_part)
{
    __shared__ __align__(16) short Q_lds[QBLK * 40];
    __shared__ __align__(16) short K_lds[KBLK * 40];     // reused as Opart[2][32][36] f32
    __shared__ __align__(16) short Vt_lds[DHEAD * 136];
    __shared__ __align__(16) unsigned int P32[QBLK * 68];
    __shared__ unsigned int ttm8[KBLK / 4];
    __shared__ float tcol_s[KBLK];
    __shared__ float tt_h[64];
    __shared__ float temp_h[21];
    __shared__ float adj_h[12];
    __shared__ float2 ml[2][QBLK];

    const int h  = blockIdx.y;
    const int n0 = blockIdx.x * QBLK;
    const int sblk = blockIdx.z;
    const int t  = threadIdx.x;
    const int wv = t >> 6, lane = t & 63, c = lane & 15, g = lane >> 4;
    const int rowblk  = (wv & 1) * 16;
    const int halfIdx = wv >> 1;
    const int colhalf = halfIdx * 64;
    const int seed = seed_ptr[0];
    const bool blockTemporal = (n0 < seed);
    const int gt0 = sblk * TPS;

    // ---- one-time staging: Q, tables ----
    if (t < 128) {
        int row = t >> 2, off = (t & 3) * 8;
        *(short8*)&Q_lds[row * 40 + off] =
            *(const short8*)&qk[(size_t)(n0 + row) * 512 + h * 32 + off];
    }
    if (t < 64)  tt_h[t] = typepair_bias[t * HHEADS + h];
    if (t < 21)  temp_h[t] = temp_bias[t * HHEADS + h];
    if (t < 12)  adj_h[t] = adj_rel_bias[t * HHEADS + h];

    const int nrow = n0 + rowblk + c;
    const int ttn = token_type[nrow];
    const bool rowTemporal = (nrow < seed);
    const float tn = time_vec[nrow];

    // prefetch registers + fixed per-thread staging slots
    const int krow = t >> 2, koff = (t & 3) * 8;       // K: rows krow, krow+64
    const int vrow = t >> 4, voff = (t & 15) * 8;      // Vt: rows vrow, vrow+16
    short8 kr0, kr1, vr0, vr1;
    int4 ttr; float tcr = 0.0f;

    auto LOADT = [&](int gt) {
        int m0 = gt * KBLK;
        const short* kp = &qk[(size_t)(m0 + krow) * 512 + 256 + h * 32 + koff];
        kr0 = *(const short8*)kp;
        kr1 = *(const short8*)(kp + (size_t)64 * 512);
        const short* vp = &vt[(size_t)(h * 32 + vrow) * NTOK + m0 + voff];
        vr0 = *(const short8*)vp;
        vr1 = *(const short8*)(vp + (size_t)16 * NTOK);
        if (t < 32) ttr = *(const int4*)&token_type[m0 + t * 4];
        if (blockTemporal && t < 128) tcr = time_vec[m0 + t];
    };
    auto WRITET = [&]() {
        *(short8*)&K_lds[krow * 40 + koff]        = kr0;
        *(short8*)&K_lds[(krow + 64) * 40 + koff] = kr1;
        *(short8*)&Vt_lds[vrow * 136 + voff]        = vr0;
        *(short8*)&Vt_lds[(vrow + 16) * 136 + voff] = vr1;
        if (t < 32)
            ttm8[t] = (unsigned)(ttr.x | (ttr.y << 8) | (ttr.z << 16) | (ttr.w << 24));
        if (blockTemporal && t < 128) tcol_s[t] = tcr;
    };

    float m_run = -INFINITY, l_run = 0.0f;
    f32x4 oacc[2] = {{0,0,0,0},{0,0,0,0}};
    const f32x4 zf = {0.0f, 0.0f, 0.0f, 0.0f};

    LOADT(gt0);
    WRITET();

    for (int tile = 0; tile < TPS; ++tile) {
        __syncthreads();                       // staged tile visible
        if (tile + 1 < TPS) LOADT(gt0 + tile + 1);   // prefetch next (no wait)

        // ---- swapped QK^T: vals[blk*4+reg] = S[q=rowblk+c][colhalf+16blk+4g+reg]
        short8 qfrag = *(const short8*)&Q_lds[(rowblk + c) * 40 + g * 8];
        float vals[16];
        #pragma unroll
        for (int blk = 0; blk < 4; blk++) {
            short8 kf = *(const short8*)&K_lds[(colhalf + blk * 16 + c) * 40 + g * 8];
            f32x4 acc = __builtin_amdgcn_mfma_f32_16x16x32_bf16(kf, qfrag, zf, 0, 0, 0);
            #pragma unroll
            for (int reg = 0; reg < 4; reg++) vals[blk * 4 + reg] = acc[reg];
        }

        // ---- typepair bias ----
        #pragma unroll
        for (int blk = 0; blk < 4; blk++) {
            unsigned w4 = ttm8[halfIdx * 16 + blk * 4 + g];
            #pragma unroll
            for (int reg = 0; reg < 4; reg++) {
                int ty = (w4 >> (8 * reg)) & 0xFF;
                vals[blk * 4 + reg] += tt_h[ttn * 8 + ty];
            }
        }
        // ---- temporal bias (rows < seed only) ----
        if (rowTemporal) {
            #pragma unroll
            for (int blk = 0; blk < 4; blk++) {
                #pragma unroll
                for (int reg = 0; reg < 4; reg++) {
                    float dt = tcol_s[colhalf + blk * 16 + g * 4 + reg] - tn;
                    float ab = fabsf(dt) + 1e-6f;
                    float sg = (dt > 0.0f) ? 1.0f : ((dt < 0.0f) ? -1.0f : 0.0f);
                    float sl = sg * log1pf(ab);
                    sl = fminf(fmaxf(sl, -5.0f), 5.0f);
                    float norm = (sl + 5.0f) * (1.0f / (10.0f + 1e-9f));
                    int bidx = (int)floorf(norm * 20.0f);
                    bidx = min(max(bidx, 0), 20);
                    vals[blk * 4 + reg] += temp_h[bidx];
                }
            }
        }
        // ---- sparse edge bias: bucket == global tile (128-wide) ----
        {
            int nidx = nrow * NTILE + gt0 + tile;
            int e0 = row_ptr2[nidx], e1 = row_ptr2[nidx + 1];
            for (int e = e0; e < e1; ++e) {
                int2 pr = pairs2[e];
                int dloc = pr.x & 127;
                if ((dloc >> 6) == halfIdx) {
                    int ml64 = dloc & 63;
                    if (((ml64 >> 2) & 3) == g) {
                        float ab = adj_h[pr.y];
                        int li = (ml64 >> 4) * 4 + (ml64 & 3);
                        #pragma unroll
                        for (int i = 0; i < 16; i++) vals[i] += (i == li) ? ab : 0.0f;
                    }
                }
            }
        }

        // ---- online softmax, lane-local row; reduce over 4 g-lanes ----
        float tmax = vals[0];
        #pragma unroll
        for (int i = 1; i < 16; i++) tmax = fmaxf(tmax, vals[i]);
        tmax = fmaxf(tmax, __shfl_xor(tmax, 16));
        tmax = fmaxf(tmax, __shfl_xor(tmax, 32));
        float m_new = fmaxf(m_run, tmax);
        float psum = 0.0f;
        #pragma unroll
        for (int i = 0; i < 16; i++) { vals[i] = __expf(vals[i] - m_new); psum += vals[i]; }
        psum += __shfl_xor(psum, 16);
        psum += __shfl_xor(psum, 32);
        float scale = __expf(m_run - m_new);
        m_run = m_new;
        l_run = l_run * scale + psum;

        // ---- pack P (bf16 pairs); same-wave consume, no barrier ----
        #pragma unroll
        for (int blk = 0; blk < 4; blk++) {
            #pragma unroll
            for (int r = 0; r < 2; r++) {
                unsigned lo = (unsigned short)f2bf(vals[blk * 4 + 2 * r]);
                unsigned hi = (unsigned short)f2bf(vals[blk * 4 + 2 * r + 1]);
                P32[(rowblk + c) * 68 + halfIdx * 32 + blk * 8 + g * 2 + r] = lo | (hi << 16);
            }
        }

        // ---- PV: rescale O, accumulate over this wave's 64-col half ----
        float scr[4];
        #pragma unroll
        for (int reg = 0; reg < 4; reg++) scr[reg] = __shfl(scale, 4 * g + reg);
        #pragma unroll
        for (int dblk = 0; dblk < 2; dblk++)
            #pragma unroll
            for (int reg = 0; reg < 4; reg++) oacc[dblk][reg] *= scr[reg];
        #pragma unroll
        for (int kc = 0; kc < 2; kc++) {
            short8 pa = *(const short8*)&P32[(rowblk + c) * 68 + halfIdx * 32 + kc * 16 + g * 4];
            #pragma unroll
            for (int dblk = 0; dblk < 2; dblk++) {
                short8 vb = *(const short8*)&Vt_lds[(dblk * 16 + c) * 136 + colhalf + kc * 32 + g * 8];
                oacc[dblk] = __builtin_amdgcn_mfma_f32_16x16x32_bf16(pa, vb, oacc[dblk], 0, 0, 0);
            }
        }

        __syncthreads();                       // all LDS reads of this tile done
        if (tile + 1 < TPS) WRITET();          // stage next tile
    }

    // ---- endgame: merge the two col-half partials, write split partial ----
    __syncthreads();
    if (lane < 16) ml[halfIdx][rowblk + lane] = make_float2(m_run, l_run);
    __syncthreads();

    float* Op = (float*)K_lds;   // [2][32][36]
    #pragma unroll
    for (int reg = 0; reg < 4; reg++) {
        int rw = rowblk + 4 * g + reg;
        float2 a0 = ml[0][rw], a1 = ml[1][rw];
        float mm = fmaxf(a0.x, a1.x);
        float wh = __expf((halfIdx == 0 ? a0.x : a1.x) - mm);
        Op[halfIdx * 32 * 36 + rw * 36 + c]      = oacc[0][reg] * wh;
        Op[halfIdx * 32 * 36 + rw * 36 + 16 + c] = oacc[1][reg] * wh;
    }
    __syncthreads();

    {
        int row = t >> 3, d0 = (t & 7) * 4;
        float2 a0 = ml[0][row], a1 = ml[1][row];
        float mm = fmaxf(a0.x, a1.x);
        float w0 = __expf(a0.x - mm), w1 = __expf(a1.x - mm);
        float lc = a0.y * w0 + a1.y * w1;
        float4 pa = *(const float4*)&Op[row * 36 + d0];
        float4 pb = *(const float4*)&Op[(32 + row) * 36 + d0];
        float4 sum;
        sum.x = pa.x + pb.x; sum.y = pa.y + pb.y;
        sum.z = pa.z + pb.z; sum.w = pa.w + pb.w;
        *(float4*)&Op_part[((size_t)sblk * NTOK + n0 + row) * CDIM + h * DHEAD + d0] = sum;
        if ((t & 7) == 0)
            ml_part[((size_t)sblk * NTOK + n0 + row) * HHEADS + h] = make_float2(mm, lc);
    }
}

// merge SPLITS partials -> o bf16. grid 2048, 256 thr (h = t>>5, d = t&31)
__global__ __launch_bounds__(256) void attn_reduce_kernel(
    const float* __restrict__ Op_part, const float2* __restrict__ ml_part,
    short* __restrict__ o)
{
    int row = blockIdx.x;
    int t = threadIdx.x;
    int h = t >> 5, d = t & 31;

    float2 a0 = ml_part[((size_t)0 * NTOK + row) * HHEADS + h];
    float2 a1 = ml_part[((size_t)1 * NTOK + row) * HHEADS + h];
    float2 a2 = ml_part[((size_t)2 * NTOK + row) * HHEADS + h];
    float2 a3 = ml_part[((size_t)3 * NTOK + row) * HHEADS + h];
    float mm = fmaxf(fmaxf(a0.x, a1.x), fmaxf(a2.x, a3.x));
    float w0 = __expf(a0.x - mm), w1 = __expf(a1.x - mm);
    float w2 = __expf(a2.x - mm), w3 = __expf(a3.x - mm);
    float l = a0.y * w0 + a1.y * w1 + a2.y * w2 + a3.y * w3;
    float inv = 1.0f / l;
    size_t idx = (size_t)row * CDIM + h * DHEAD + d;
    float acc = w0 * Op_part[(size_t)0 * NTOK * CDIM + idx]
              + w1 * Op_part[(size_t)1 * NTOK * CDIM + idx]
              + w2 * Op_part[(size_t)2 * NTOK * CDIM + idx]
              + w3 * Op_part[(size_t)3 * NTOK * CDIM + idx];
    o[idx] = f2bf(acc * inv);
}

// ---------------- launch --------------------------------------------------------
extern "C" void kernel_launch(void* const* d_in, const int* in_sizes, int n_in,
                              void* d_out, int out_size, void* d_ws, size_t ws_size,
                              hipStream_t stream)
{
    (void)in_sizes; (void)n_in; (void)out_size; (void)ws_size;
    const float* X        = (const float*)d_in[0];
    const int* token_type = (const int*)d_in[1];
    const int* edge_src   = (const int*)d_in[2];
    const int* edge_dst   = (const int*)d_in[3];
    const int* edge_rel   = (const int*)d_in[4];
    const float* time_vec = (const float*)d_in[5];
    const int* seed_ptr   = (const int*)d_in[6];
    const float* Wq = (const float*)d_in[7];  const float* bq = (const float*)d_in[8];
    const float* Wk = (const float*)d_in[9];  const float* bk = (const float*)d_in[10];
    const float* Wv = (const float*)d_in[11]; const float* bv = (const float*)d_in[12];
    const float* Wo = (const float*)d_in[13]; const float* bo = (const float*)d_in[14];
    const float* ln1_g = (const float*)d_in[15]; const float* ln1_b = (const float*)d_in[16];
    const float* ln2_g = (const float*)d_in[17]; const float* ln2_b = (const float*)d_in[18];
    const float* W1 = (const float*)d_in[19]; const float* b1 = (const float*)d_in[20];
    const float* W2 = (const float*)d_in[21]; const float* b2 = (const float*)d_in[22];
    const float* adj_rel_bias  = (const float*)d_in[23];
    const float* typepair_bias = (const float*)d_in[24];
    const float* temp_bias     = (const float*)d_in[25];
    float* out = (float*)d_out;

    char* base = (char*)d_ws;
    size_t off = 0;
    auto alloc = [&](size_t bytes) { char* p = base + off; off += (bytes + 255) & ~(size_t)255; return p; };
    short* qk_bf   = (short*)alloc((size_t)NTOK * 512 * 2);
    short* v_bf    = (short*)alloc((size_t)NTOK * 256 * 2);
    short* vt_bf   = (short*)alloc((size_t)256 * NTOK * 2);
    short* h1_bf   = (short*)alloc((size_t)NTOK * 256 * 2);
    short* h2_bf   = (short*)alloc((size_t)NTOK * 256 * 2);
    short* o_bf    = (short*)alloc((size_t)NTOK * 256 * 2);
    short* mid_bf  = (short*)alloc((size_t)NTOK * 1024 * 2);
    float* xb      = (float*)alloc((size_t)NTOK * 256 * 4);
    short* wt_qkv  = (short*)alloc((size_t)768 * 256 * 2);
    short* wot     = (short*)alloc((size_t)256 * 256 * 2);
    short* w1t     = (short*)alloc((size_t)1024 * 256 * 2);
    short* w2t     = (short*)alloc((size_t)256 * 1024 * 2);
    int2*  pairs2  = (int2*)alloc((size_t)NEDGE * 8);
    int*   cnt2    = (int*)alloc((size_t)NTOK * NTILE * 4);
    int*   rowptr2 = (int*)alloc(((size_t)NTOK * NTILE + 1) * 4);
    int*   wcur2   = (int*)alloc((size_t)NTOK * NTILE * 4);
    float* Op_part = (float*)alloc((size_t)SPLITS * NTOK * CDIM * 4);   // 8 MB
    float2* ml_part = (float2*)alloc((size_t)SPLITS * NTOK * HHEADS * 8);

    // all weight transposes in one launch
    transpose_all_kernel<<<192, 256, 0, stream>>>(Wq, Wk, Wv, Wo, W1, W2,
                                                  wt_qkv, wot, w1t, w2t);

    // LN1 -> bf16
    ln_kernel<<<NTOK, 256, 0, stream>>>(X, ln1_g, ln1_b, h1_bf);

    // fused QKV projection (q pre-scaled)
    gemm_qkv_kernel<<<dim3(12, 32), 256, 0, stream>>>(h1_bf, wt_qkv, bq, bk, bv, qk_bf, v_bf);

    // V^T for attention
    transpose_kernel<<<dim3(4, 32), 256, 0, stream>>>(v_bf, vt_bf, NTOK, 256);

    // edge CSR bucketed by (src, dst>>7)
    hipMemsetAsync(cnt2, 0, NTOK * NTILE * sizeof(int), stream);
    edge_hist2_kernel<<<NEDGE / 256, 256, 0, stream>>>(edge_src, edge_dst, cnt2, NEDGE);
    edge_scan2_kernel<<<1, 256, 0, stream>>>(cnt2, rowptr2, wcur2);
    edge_scatter2_kernel<<<NEDGE / 256, 256, 0, stream>>>(edge_src, edge_dst, edge_rel, wcur2, pairs2, NEDGE);

    // fused MFMA attention (split-K) -> partials, then reduce -> o (bf16)
    attn_mfma3_kernel<<<dim3(NTOK / QBLK, HHEADS, SPLITS), 256, 0, stream>>>(
        qk_bf, vt_bf, token_type, time_vec, seed_ptr,
        adj_rel_bias, typepair_bias, temp_bias, rowptr2, pairs2, Op_part, ml_part);
    attn_reduce_kernel<<<NTOK, 256, 0, stream>>>(Op_part, ml_part, o_bf);

    // x = X + o @ Wo + bo   (f32 out)
    gemm_bf16_kernel<2><<<dim3(4, 32), 256, 0, stream>>>(o_bf, wot, bo, X, xb, NTOK, 256, 256);

    // LN2 -> bf16
    ln_kernel<<<NTOK, 256, 0, stream>>>(xb, ln2_g, ln2_b, h2_bf);

    // FFN
    gemm_bf16_kernel<3><<<dim3(16, 32), 256, 0, stream>>>(h2_bf, w1t, b1, nullptr, mid_bf, NTOK, 1024, 256);
    gemm_bf16_kernel<2><<<dim3(4, 32), 256, 0, stream>>>(mid_bf, w2t, b2, xb, out, NTOK, 256, 1024);
}